// Round 11
// baseline (877.563 us; speedup 1.0000x reference)
//
#include <hip/hip_runtime.h>

#define DD 64
#define POOL_NPB 512
#define EPB 1024  // edges per block in fill pipeline

// f32 -> bf16 (RNE), result in low 16 bits
__device__ __forceinline__ unsigned f2bf(float x) {
  unsigned u = __float_as_uint(x);
  return (u + 0x7fffu + ((u >> 16) & 1u)) >> 16;
}

// ================= coarse histogram (LDS only) =================
__global__ __launch_bounds__(256) void k_hist(const int* __restrict__ dst,
                                              int* __restrict__ chist, int E) {
  __shared__ int lh[256];
  lh[threadIdx.x] = 0;
  __syncthreads();
  const int base = blockIdx.x * EPB;
#pragma unroll
  for (int k = 0; k < EPB / 256; ++k) {
    const int e = base + k * 256 + threadIdx.x;
    if (e < E) atomicAdd(&lh[dst[e] >> 8], 1);
  }
  __syncthreads();
  const int v = lh[threadIdx.x];
  if (v) atomicAdd(&chist[threadIdx.x], v);
}

// ---- scan of coarse histogram -> gcur (mutable) + cbase (stable) ----
__global__ __launch_bounds__(256) void cscan(const int* __restrict__ chist,
                                             int* __restrict__ gcur,
                                             int* __restrict__ cbase) {
  __shared__ int s[256];
  const int t = threadIdx.x;
  const int v = chist[t];
  s[t] = v;
  __syncthreads();
#pragma unroll
  for (int off = 1; off < 256; off <<= 1) {
    const int add = (t >= off) ? s[t - off] : 0;
    __syncthreads();
    s[t] += add;
    __syncthreads();
  }
  const int ex = s[t] - v;
  gcur[t] = ex;
  cbase[t] = ex;
}

// ---- coarse scatter: LDS-reordered, bucket-contiguous 4B packed records ----
__global__ __launch_bounds__(256) void f2_coarse(
    const int* __restrict__ src, const int* __restrict__ dst,
    const int* __restrict__ et, int* __restrict__ gcur,
    unsigned* __restrict__ staging, int E) {
  __shared__ int lcnt[256];
  __shared__ int sc[256];
  __shared__ int lbase[256];
  __shared__ int gb[256];
  __shared__ unsigned rec[EPB];
  __shared__ unsigned char rbk[EPB];

  const int t = threadIdx.x;
  const int base = blockIdx.x * EPB;
  const int bc = min(EPB, E - base);

  lcnt[t] = 0;
  __syncthreads();

  int d_[EPB / 256], se_[EPB / 256], rk_[EPB / 256];
#pragma unroll
  for (int k = 0; k < EPB / 256; ++k) {
    const int e = base + k * 256 + t;
    if (e < E) {
      const int d = dst[e];
      d_[k] = d;
      se_[k] = (src[e] << 2) | et[e];
      rk_[k] = atomicAdd(&lcnt[d >> 8], 1);
    } else {
      d_[k] = -1;
    }
  }
  __syncthreads();

  const int lv = lcnt[t];
  sc[t] = lv;
  __syncthreads();
#pragma unroll
  for (int off = 1; off < 256; off <<= 1) {
    const int add = (t >= off) ? sc[t - off] : 0;
    __syncthreads();
    sc[t] += add;
    __syncthreads();
  }
  lbase[t] = sc[t] - lv;
  gb[t] = lv ? atomicAdd(&gcur[t], lv) : 0;
  __syncthreads();

#pragma unroll
  for (int k = 0; k < EPB / 256; ++k) {
    if (d_[k] >= 0) {
      const int cb = d_[k] >> 8;
      const int pos = lbase[cb] + rk_[k];
      rec[pos] = ((unsigned)(d_[k] & 255) << 24) | (unsigned)se_[k];
      rbk[pos] = (unsigned char)cb;
    }
  }
  __syncthreads();

  for (int idx = t; idx < bc; idx += 256) {
    const int cb = rbk[idx];
    staging[gb[cb] + (idx - lbase[cb])] = rec[idx];
  }
}

// ---- fine placement, 1024 bins = (d&255)*4 + rel: (dst,rel)-sorted ----
__global__ __launch_bounds__(1024) void f3_fine3(
    const unsigned* __restrict__ staging, const int* __restrict__ cbase,
    int* __restrict__ rowptr, int* __restrict__ srcet, int N, int E, int ncb) {
  __shared__ int ldeg[1024];
  __shared__ int sc[1024];
  __shared__ int lcur[1024];
  const int cb = blockIdx.x;
  const int t = threadIdx.x;
  const int s0 = cbase[cb];
  const int s1 = (cb + 1 < ncb) ? cbase[cb + 1] : E;

  ldeg[t] = 0;
  __syncthreads();
  for (int i = s0 + t; i < s1; i += 1024) {
    const unsigned r = staging[i];
    atomicAdd(&ldeg[((r >> 24) << 2) | (r & 3u)], 1);
  }
  __syncthreads();

  const int v = ldeg[t];
  sc[t] = v;
  __syncthreads();
#pragma unroll
  for (int off = 1; off < 1024; off <<= 1) {
    const int add = (t >= off) ? sc[t - off] : 0;
    __syncthreads();
    sc[t] += add;
    __syncthreads();
  }
  const int base = s0 + sc[t] - v;
  lcur[t] = base;
  if ((t & 3) == 0) {
    const int dn = (cb << 8) + (t >> 2);
    if (dn < N) rowptr[dn] = base;
  }
  if (cb == ncb - 1 && t == 0) rowptr[N] = E;
  __syncthreads();

  for (int i = s0 + t; i < s1; i += 1024) {
    const unsigned r = staging[i];
    const int pos = atomicAdd(&lcur[((r >> 24) << 2) | (r & 3u)], 1);
    srcet[pos] = (int)(r & 0xFFFFFFu);
  }
}

// ================= f32 -> bf16 conversion =================
__global__ __launch_bounds__(256) void conv_bf16(const float* __restrict__ x,
                                                 ushort* __restrict__ xb,
                                                 int n4) {
  int i = blockIdx.x * 256 + threadIdx.x;
  if (i < n4) {
    float4 v = ((const float4*)x)[i];
    uint2 o;
    o.x = f2bf(v.x) | (f2bf(v.y) << 16);
    o.y = f2bf(v.z) | (f2bf(v.w) << 16);
    ((uint2*)xb)[i] = o;
  }
}

#define UNPACK8(raw, v)                               \
  v[0] = __uint_as_float(raw.x << 16);                \
  v[1] = __uint_as_float(raw.x & 0xffff0000u);        \
  v[2] = __uint_as_float(raw.y << 16);                \
  v[3] = __uint_as_float(raw.y & 0xffff0000u);        \
  v[4] = __uint_as_float(raw.z << 16);                \
  v[5] = __uint_as_float(raw.z & 0xffff0000u);        \
  v[6] = __uint_as_float(raw.w << 16);                \
  v[7] = __uint_as_float(raw.w & 0xffff0000u);

// ============ per-node relation gather (bf16 rows, sorted, 8x8) ============
__global__ __launch_bounds__(256) void gather_rel_b(
    const ushort* __restrict__ hb, const int* __restrict__ rowptr,
    const int* __restrict__ srcet, float* __restrict__ aggr, int N) {
  const int n = blockIdx.x * 4 + (threadIdx.x >> 6);
  const int lane = threadIdx.x & 63;
  const int g = lane >> 3;  // edge slot 0..7
  const int t = lane & 7;   // 16B chunk (8 bf16)
  if (n >= N) return;
  const int beg = rowptr[n], end = rowptr[n + 1];

  float a0[8], a1[8], a2[8], a3[8];
#pragma unroll
  for (int k = 0; k < 8; ++k) { a0[k] = 0.f; a1[k] = 0.f; a2[k] = 0.f; a3[k] = 0.f; }

  int j = beg + g;
  for (; j + 8 < end; j += 16) {
    const int se0 = srcet[j];
    const int se1 = srcet[j + 8];
    const uint4 raw0 = *(const uint4*)(hb + ((size_t)(se0 >> 2) << 6) + (t << 3));
    const uint4 raw1 = *(const uint4*)(hb + ((size_t)(se1 >> 2) << 6) + (t << 3));
    float v0[8], v1[8];
    UNPACK8(raw0, v0);
    UNPACK8(raw1, v1);
    const int r0 = se0 & 3;
    if (r0 == 0) {
#pragma unroll
      for (int k = 0; k < 8; ++k) a0[k] += v0[k];
    } else if (r0 == 1) {
#pragma unroll
      for (int k = 0; k < 8; ++k) a1[k] += v0[k];
    } else if (r0 == 2) {
#pragma unroll
      for (int k = 0; k < 8; ++k) a2[k] += v0[k];
    } else {
#pragma unroll
      for (int k = 0; k < 8; ++k) a3[k] += v0[k];
    }
    const int r1 = se1 & 3;
    if (r1 == 0) {
#pragma unroll
      for (int k = 0; k < 8; ++k) a0[k] += v1[k];
    } else if (r1 == 1) {
#pragma unroll
      for (int k = 0; k < 8; ++k) a1[k] += v1[k];
    } else if (r1 == 2) {
#pragma unroll
      for (int k = 0; k < 8; ++k) a2[k] += v1[k];
    } else {
#pragma unroll
      for (int k = 0; k < 8; ++k) a3[k] += v1[k];
    }
  }
  if (j < end) {
    const int se0 = srcet[j];
    const uint4 raw0 = *(const uint4*)(hb + ((size_t)(se0 >> 2) << 6) + (t << 3));
    float v0[8];
    UNPACK8(raw0, v0);
    const int r0 = se0 & 3;
    if (r0 == 0) {
#pragma unroll
      for (int k = 0; k < 8; ++k) a0[k] += v0[k];
    } else if (r0 == 1) {
#pragma unroll
      for (int k = 0; k < 8; ++k) a1[k] += v0[k];
    } else if (r0 == 2) {
#pragma unroll
      for (int k = 0; k < 8; ++k) a2[k] += v0[k];
    } else {
#pragma unroll
      for (int k = 0; k < 8; ++k) a3[k] += v0[k];
    }
  }

#pragma unroll
  for (int off = 8; off <= 32; off <<= 1) {
#pragma unroll
    for (int k = 0; k < 8; ++k) {
      a0[k] += __shfl_xor(a0[k], off);
      a1[k] += __shfl_xor(a1[k], off);
      a2[k] += __shfl_xor(a2[k], off);
      a3[k] += __shfl_xor(a3[k], off);
    }
  }

  if (g < 4) {
    float r8[8];
    if (g == 0) {
#pragma unroll
      for (int k = 0; k < 8; ++k) r8[k] = a0[k];
    } else if (g == 1) {
#pragma unroll
      for (int k = 0; k < 8; ++k) r8[k] = a1[k];
    } else if (g == 2) {
#pragma unroll
      for (int k = 0; k < 8; ++k) r8[k] = a2[k];
    } else {
#pragma unroll
      for (int k = 0; k < 8; ++k) r8[k] = a3[k];
    }
    float* o = aggr + ((size_t)n << 8) + (g << 6) + (t << 3);
    *(float4*)(o + 0) = make_float4(r8[0], r8[1], r8[2], r8[3]);
    *(float4*)(o + 4) = make_float4(r8[4], r8[5], r8[6], r8[7]);
  }
}

// ====== dense: hb_out = bf16(relu(sum_r aggr[r]@Wrel[r] + hb_in@Wloop + brel)) ======
__global__ __launch_bounds__(256) void rgcn_dense_b(
    const float* __restrict__ aggr, const ushort* __restrict__ hb_in,
    const float* __restrict__ Wrel, const float* __restrict__ Wloop,
    const float* __restrict__ brel, ushort* __restrict__ hb_out, int N) {
  const int lane = threadIdx.x & 63;
  const int wv = threadIdx.x >> 6;
  const int c0 = __builtin_amdgcn_readfirstlane(wv << 4);
  const int n = blockIdx.x * 64 + lane;

  float acc[16];
#pragma unroll
  for (int jj = 0; jj < 16; ++jj) acc[jj] = brel[c0 + jj];

  float in[DD];
#pragma unroll 1
  for (int m = 0; m < 5; ++m) {
    const float* __restrict__ W =
        (m < 4) ? (Wrel + (size_t)m * DD * DD) : Wloop;
    if (n < N) {
      if (m < 4) {
        const float4* p = (const float4*)(aggr + ((size_t)n << 8) + (m << 6));
#pragma unroll
        for (int t = 0; t < DD / 4; ++t) {
          float4 v = p[t];
          in[4 * t + 0] = v.x; in[4 * t + 1] = v.y;
          in[4 * t + 2] = v.z; in[4 * t + 3] = v.w;
        }
      } else {
        const uint4* p = (const uint4*)(hb_in + ((size_t)n << 6));
#pragma unroll
        for (int q = 0; q < 8; ++q) {
          const uint4 raw = p[q];
          float* vp = in + 8 * q;
          UNPACK8(raw, vp);
        }
      }
    } else {
#pragma unroll
      for (int t = 0; t < DD; ++t) in[t] = 0.f;
    }
#pragma unroll
    for (int k = 0; k < DD; ++k) {
      const float hk = in[k];
#pragma unroll
      for (int jj = 0; jj < 16; ++jj)
        acc[jj] = fmaf(hk, W[k * DD + c0 + jj], acc[jj]);
    }
  }
  if (n < N) {
    uint u[8];
#pragma unroll
    for (int jj = 0; jj < 8; ++jj) {
      const float x0 = fmaxf(acc[2 * jj + 0], 0.f);
      const float x1 = fmaxf(acc[2 * jj + 1], 0.f);
      u[jj] = f2bf(x0) | (f2bf(x1) << 16);
    }
    uint4* o = (uint4*)(hb_out + ((size_t)n << 6) + c0);
    o[0] = make_uint4(u[0], u[1], u[2], u[3]);
    o[1] = make_uint4(u[4], u[5], u[6], u[7]);
  }
}

// ====== GAT projection: zb = bf16(h@Wg); el/er fused ======
__global__ __launch_bounds__(256) void gemm_gat(
    const ushort* __restrict__ hb_in, const float* __restrict__ Wg,
    const float* __restrict__ al, const float* __restrict__ ar,
    ushort* __restrict__ zb, float* __restrict__ el, float* __restrict__ er,
    int N) {
  __shared__ float sel[4][64];
  __shared__ float ser[4][64];
  const int lane = threadIdx.x & 63;
  const int wv = threadIdx.x >> 6;
  const int c0 = __builtin_amdgcn_readfirstlane(wv << 4);
  const int n = blockIdx.x * 64 + lane;

  float in[DD];
  if (n < N) {
    const uint4* p = (const uint4*)(hb_in + ((size_t)n << 6));
#pragma unroll
    for (int q = 0; q < 8; ++q) {
      const uint4 raw = p[q];
      float* vp = in + 8 * q;
      UNPACK8(raw, vp);
    }
  } else {
#pragma unroll
    for (int t = 0; t < DD; ++t) in[t] = 0.f;
  }

  float acc[16];
#pragma unroll
  for (int jj = 0; jj < 16; ++jj) acc[jj] = 0.f;
#pragma unroll
  for (int k = 0; k < DD; ++k) {
    const float hk = in[k];
#pragma unroll
    for (int jj = 0; jj < 16; ++jj)
      acc[jj] = fmaf(hk, Wg[k * DD + c0 + jj], acc[jj]);
  }

  float pl = 0.f, pr = 0.f;
#pragma unroll
  for (int jj = 0; jj < 16; ++jj) {
    pl = fmaf(acc[jj], al[c0 + jj], pl);
    pr = fmaf(acc[jj], ar[c0 + jj], pr);
  }
  sel[wv][lane] = pl;
  ser[wv][lane] = pr;
  __syncthreads();
  if (wv == 0 && n < N) {
    el[n] = sel[0][lane] + sel[1][lane] + sel[2][lane] + sel[3][lane];
    er[n] = ser[0][lane] + ser[1][lane] + ser[2][lane] + ser[3][lane];
  }

  if (n < N) {
    uint u[8];
#pragma unroll
    for (int jj = 0; jj < 8; ++jj)
      u[jj] = f2bf(acc[2 * jj + 0]) | (f2bf(acc[2 * jj + 1]) << 16);
    uint4* o = (uint4*)(zb + ((size_t)n << 6) + c0);
    o[0] = make_uint4(u[0], u[1], u[2], u[3]);
    o[1] = make_uint4(u[4], u[5], u[6], u[7]);
  }
}

// ============ fused GAT aggregation (bf16 z rows, 8x8) ============
__global__ __launch_bounds__(256) void gat_fused_b(
    const ushort* __restrict__ zb, const float* __restrict__ el,
    const float* __restrict__ er, const int* __restrict__ rowptr,
    const int* __restrict__ srcet, float* __restrict__ hg, int N) {
  const int n = blockIdx.x * 4 + (threadIdx.x >> 6);
  const int lane = threadIdx.x & 63;
  const int g = lane >> 3;
  const int t = lane & 7;
  if (n >= N) return;
  const int beg = rowptr[n], end = rowptr[n + 1];
  const float ern = er[n];

  // phase A: online (m, den), 64 edges in flight
  float m = -1e30f, den = 0.f;
  for (int j = beg + lane; j < end; j += 64) {
    const int s = srcet[j] >> 2;
    float x = el[s] + ern;
    x = (x > 0.f) ? x : 0.2f * x;
    if (x > m) {
      den *= __expf(m - x);
      m = x;
    }
    den += __expf(x - m);
  }
#pragma unroll
  for (int off = 1; off < 64; off <<= 1) {
    float mo = __shfl_xor(m, off);
    float dn = __shfl_xor(den, off);
    float M = fmaxf(m, mo);
    den = den * __expf(m - M) + dn * __expf(mo - M);
    m = M;
  }

  // phase B: weighted gather, 8 edges in flight
  float num[8];
#pragma unroll
  for (int k = 0; k < 8; ++k) num[k] = 0.f;
  for (int j = beg + g; j < end; j += 8) {
    const int se = srcet[j];
    const int s = se >> 2;
    float x = el[s] + ern;
    x = (x > 0.f) ? x : 0.2f * x;
    const float w = __expf(x - m);
    const uint4 raw = *(const uint4*)(zb + ((size_t)s << 6) + (t << 3));
    float v[8];
    UNPACK8(raw, v);
#pragma unroll
    for (int k = 0; k < 8; ++k) num[k] = fmaf(w, v[k], num[k]);
  }
#pragma unroll
  for (int off = 8; off <= 32; off <<= 1) {
#pragma unroll
    for (int k = 0; k < 8; ++k) num[k] += __shfl_xor(num[k], off);
  }
  if (g == 0) {
    const float inv = 1.f / fmaxf(den, 1e-9f);
    float* o = hg + ((size_t)n << 6) + (t << 3);
    *(float4*)(o + 0) =
        make_float4(num[0] * inv, num[1] * inv, num[2] * inv, num[3] * inv);
    *(float4*)(o + 4) =
        make_float4(num[4] * inv, num[5] * inv, num[6] * inv, num[7] * inv);
  }
}

// ================= pooled head, two-level =================
__global__ __launch_bounds__(256) void pool_head2(
    const float* __restrict__ hg, const float* __restrict__ Wd,
    const int* __restrict__ gids, float* __restrict__ out, int N, int B) {
  __shared__ float acc[1024];
  for (int i = threadIdx.x; i < B; i += 256) acc[i] = 0.f;
  __syncthreads();

  const int wv = threadIdx.x >> 6;
  const int lane = threadIdx.x & 63;
  const int sub = lane & 3;
  const int idx = lane >> 2;

  const float4 w0 = *(const float4*)(Wd + (sub << 4) + 0);
  const float4 w1 = *(const float4*)(Wd + (sub << 4) + 4);
  const float4 w2 = *(const float4*)(Wd + (sub << 4) + 8);
  const float4 w3 = *(const float4*)(Wd + (sub << 4) + 12);

  const int base0 = blockIdx.x * POOL_NPB;
#pragma unroll 1
  for (int it = 0; it < POOL_NPB / 64; ++it) {
    const int n = base0 + it * 64 + wv * 16 + idx;
    if (n < N) {
      const float* p = hg + ((size_t)n << 6) + (sub << 4);
      const float4 v0 = *(const float4*)(p + 0);
      const float4 v1 = *(const float4*)(p + 4);
      const float4 v2 = *(const float4*)(p + 8);
      const float4 v3 = *(const float4*)(p + 12);
      float s = v0.x * w0.x + v0.y * w0.y + v0.z * w0.z + v0.w * w0.w;
      s = fmaf(v1.x, w1.x, s); s = fmaf(v1.y, w1.y, s);
      s = fmaf(v1.z, w1.z, s); s = fmaf(v1.w, w1.w, s);
      s = fmaf(v2.x, w2.x, s); s = fmaf(v2.y, w2.y, s);
      s = fmaf(v2.z, w2.z, s); s = fmaf(v2.w, w2.w, s);
      s = fmaf(v3.x, w3.x, s); s = fmaf(v3.y, w3.y, s);
      s = fmaf(v3.z, w3.z, s); s = fmaf(v3.w, w3.w, s);
      s += __shfl_xor(s, 1);
      s += __shfl_xor(s, 2);
      if (sub == 0) atomicAdd(&acc[gids[n]], s);
    }
  }
  __syncthreads();
  for (int i = threadIdx.x; i < B; i += 256) {
    const float v = acc[i];
    if (v != 0.f) unsafeAtomicAdd(out + i, v);
  }
}

__global__ void init_out_k(float* out, const float* bd, int n) {
  int i = blockIdx.x * blockDim.x + threadIdx.x;
  if (i < n) out[i] = bd[0];
}

// ================= launch =================
extern "C" void kernel_launch(void* const* d_in, const int* in_sizes, int n_in,
                              void* d_out, int out_size, void* d_ws,
                              size_t ws_size, hipStream_t stream) {
  const float* h0 = (const float*)d_in[0];
  const float* Wrel = (const float*)d_in[1];
  const float* Wloop = (const float*)d_in[2];
  const float* brel = (const float*)d_in[3];
  const float* Wg = (const float*)d_in[4];
  const float* al = (const float*)d_in[5];
  const float* ar = (const float*)d_in[6];
  const float* Wd = (const float*)d_in[7];
  const float* bd = (const float*)d_in[8];
  const int* src = (const int*)d_in[9];
  const int* dst = (const int*)d_in[10];
  const int* et = (const int*)d_in[11];
  const int* gids = (const int*)d_in[12];

  const int N = in_sizes[0] / DD;
  const int E = in_sizes[9];
  const int L = in_sizes[2] / (DD * DD);
  float* out = (float*)d_out;

  // ---- workspace layout ----
  char* wsb = (char*)d_ws;
  ushort* hbA = (ushort*)wsb;                        // N*64 bf16
  ushort* hbB = hbA + (size_t)N * DD;                // N*64 bf16
  float* aggr = (float*)(hbB + (size_t)N * DD);      // N*256 f32
  int* rowptr = (int*)(aggr + (size_t)N * 4 * DD);   // N+1
  int* srcet = rowptr + N + 1;                       // E
  float* el = (float*)(srcet + E);                   // N
  float* er = el + N;                                // N
  int* chist = (int*)(er + N);                       // 256
  int* gcur = chist + 256;                           // 256
  int* cbase = gcur + 256;                           // 256
  unsigned* staging = (unsigned*)aggr;               // E uint, overlays aggr
  float* hg = aggr;                                  // overlay after last dense

  dim3 b256(256);
  const int grid_dense = (N + 63) / 64;
  const int grid_n4 = (N + 3) / 4;
  const int nfb = (E + EPB - 1) / EPB;
  const int ncb = (N + 255) >> 8;

  hipLaunchKernelGGL(init_out_k, dim3((out_size + 255) / 256), b256, 0, stream,
                     out, bd, out_size);

  // ---- CSR build (hierarchical fill, (dst,rel)-sorted output) ----
  hipMemsetAsync(chist, 0, 256 * 4, stream);
  hipLaunchKernelGGL(k_hist, dim3(nfb), b256, 0, stream, dst, chist, E);
  hipLaunchKernelGGL(cscan, dim3(1), b256, 0, stream, chist, gcur, cbase);
  hipLaunchKernelGGL(f2_coarse, dim3(nfb), b256, 0, stream, src, dst, et, gcur,
                     staging, E);
  hipLaunchKernelGGL(f3_fine3, dim3(ncb), dim3(1024), 0, stream, staging, cbase,
                     rowptr, srcet, N, E, ncb);

  // ---- h0 -> bf16 ----
  hipLaunchKernelGGL(conv_bf16, dim3((N * DD / 4 + 255) / 256), b256, 0, stream,
                     h0, hbA, N * DD / 4);

  // ---- RGCN layers (bf16 features, f32 accumulate) ----
  ushort* cur = hbA;
  ushort* nxt = hbB;
  for (int l = 0; l < L; ++l) {
    hipLaunchKernelGGL(gather_rel_b, dim3(grid_n4), b256, 0, stream, cur,
                       rowptr, srcet, aggr, N);
    hipLaunchKernelGGL(rgcn_dense_b, dim3(grid_dense), b256, 0, stream, aggr,
                       cur, Wrel + (size_t)l * 4 * DD * DD,
                       Wloop + (size_t)l * DD * DD, brel + (size_t)l * DD, nxt,
                       N);
    ushort* tmp = cur; cur = nxt; nxt = tmp;
  }

  // ---- GAT ----
  ushort* zb = nxt;
  hipLaunchKernelGGL(gemm_gat, dim3(grid_dense), b256, 0, stream, cur, Wg, al,
                     ar, zb, el, er, N);
  hipLaunchKernelGGL(gat_fused_b, dim3(grid_n4), b256, 0, stream, zb, el, er,
                     rowptr, srcet, hg, N);

  const int grid_pool = (N + POOL_NPB - 1) / POOL_NPB;
  hipLaunchKernelGGL(pool_head2, dim3(grid_pool), b256, 0, stream, hg, Wd, gids,
                     out, N, out_size);
}

// Round 12
// 700.590 us; speedup vs baseline: 1.2526x; 1.2526x over previous
//
#include <hip/hip_runtime.h>

#define DD 64
#define POOL_NPB 512
#define EPB 1024  // edges per block in fill pipeline

__device__ __forceinline__ unsigned enc_f32(float x) {
  unsigned u = __float_as_uint(x);
  return (u & 0x80000000u) ? ~u : (u | 0x80000000u);
}
__device__ __forceinline__ float dec_f32(unsigned k) {
  return (k & 0x80000000u) ? __uint_as_float(k ^ 0x80000000u)
                           : __uint_as_float(~k);
}

// ================= coarse histogram (LDS only) =================
__global__ __launch_bounds__(256) void k_hist(const int* __restrict__ dst,
                                              int* __restrict__ chist, int E) {
  __shared__ int lh[256];
  lh[threadIdx.x] = 0;
  __syncthreads();
  const int base = blockIdx.x * EPB;
#pragma unroll
  for (int k = 0; k < EPB / 256; ++k) {
    const int e = base + k * 256 + threadIdx.x;
    if (e < E) atomicAdd(&lh[dst[e] >> 8], 1);
  }
  __syncthreads();
  const int v = lh[threadIdx.x];
  if (v) atomicAdd(&chist[threadIdx.x], v);
}

// ---- scan of coarse histogram -> gcur (mutable) + cbase (stable) ----
__global__ __launch_bounds__(256) void cscan(const int* __restrict__ chist,
                                             int* __restrict__ gcur,
                                             int* __restrict__ cbase) {
  __shared__ int s[256];
  const int t = threadIdx.x;
  const int v = chist[t];
  s[t] = v;
  __syncthreads();
#pragma unroll
  for (int off = 1; off < 256; off <<= 1) {
    const int add = (t >= off) ? s[t - off] : 0;
    __syncthreads();
    s[t] += add;
    __syncthreads();
  }
  const int ex = s[t] - v;
  gcur[t] = ex;
  cbase[t] = ex;
}

// ---- coarse scatter: LDS-reordered, bucket-contiguous 4B packed records ----
__global__ __launch_bounds__(256) void f2_coarse(
    const int* __restrict__ src, const int* __restrict__ dst,
    const int* __restrict__ et, int* __restrict__ gcur,
    unsigned* __restrict__ staging, int E) {
  __shared__ int lcnt[256];
  __shared__ int sc[256];
  __shared__ int lbase[256];
  __shared__ int gb[256];
  __shared__ unsigned rec[EPB];
  __shared__ unsigned char rbk[EPB];

  const int t = threadIdx.x;
  const int base = blockIdx.x * EPB;
  const int bc = min(EPB, E - base);

  lcnt[t] = 0;
  __syncthreads();

  int d_[EPB / 256], se_[EPB / 256], rk_[EPB / 256];
#pragma unroll
  for (int k = 0; k < EPB / 256; ++k) {
    const int e = base + k * 256 + t;
    if (e < E) {
      const int d = dst[e];
      d_[k] = d;
      se_[k] = (src[e] << 2) | et[e];
      rk_[k] = atomicAdd(&lcnt[d >> 8], 1);
    } else {
      d_[k] = -1;
    }
  }
  __syncthreads();

  const int lv = lcnt[t];
  sc[t] = lv;
  __syncthreads();
#pragma unroll
  for (int off = 1; off < 256; off <<= 1) {
    const int add = (t >= off) ? sc[t - off] : 0;
    __syncthreads();
    sc[t] += add;
    __syncthreads();
  }
  lbase[t] = sc[t] - lv;
  gb[t] = lv ? atomicAdd(&gcur[t], lv) : 0;
  __syncthreads();

#pragma unroll
  for (int k = 0; k < EPB / 256; ++k) {
    if (d_[k] >= 0) {
      const int cb = d_[k] >> 8;
      const int pos = lbase[cb] + rk_[k];
      rec[pos] = ((unsigned)(d_[k] & 255) << 24) | (unsigned)se_[k];
      rbk[pos] = (unsigned char)cb;
    }
  }
  __syncthreads();

  for (int idx = t; idx < bc; idx += 256) {
    const int cb = rbk[idx];
    staging[gb[cb] + (idx - lbase[cb])] = rec[idx];
  }
}

// ---- fine placement, 1024 bins = (d&255)*4 + rel: (dst,rel)-sorted ----
__global__ __launch_bounds__(1024) void f3_fine3(
    const unsigned* __restrict__ staging, const int* __restrict__ cbase,
    int* __restrict__ rowptr, int* __restrict__ srcet, int N, int E, int ncb) {
  __shared__ int ldeg[1024];
  __shared__ int sc[1024];
  __shared__ int lcur[1024];
  const int cb = blockIdx.x;
  const int t = threadIdx.x;
  const int s0 = cbase[cb];
  const int s1 = (cb + 1 < ncb) ? cbase[cb + 1] : E;

  ldeg[t] = 0;
  __syncthreads();
  for (int i = s0 + t; i < s1; i += 1024) {
    const unsigned r = staging[i];
    atomicAdd(&ldeg[((r >> 24) << 2) | (r & 3u)], 1);
  }
  __syncthreads();

  const int v = ldeg[t];
  sc[t] = v;
  __syncthreads();
#pragma unroll
  for (int off = 1; off < 1024; off <<= 1) {
    const int add = (t >= off) ? sc[t - off] : 0;
    __syncthreads();
    sc[t] += add;
    __syncthreads();
  }
  const int base = s0 + sc[t] - v;
  lcur[t] = base;
  if ((t & 3) == 0) {
    const int dn = (cb << 8) + (t >> 2);
    if (dn < N) rowptr[dn] = base;
  }
  if (cb == ncb - 1 && t == 0) rowptr[N] = E;
  __syncthreads();

  for (int i = s0 + t; i < s1; i += 1024) {
    const unsigned r = staging[i];
    const int pos = atomicAdd(&lcur[((r >> 24) << 2) | (r & 3u)], 1);
    srcet[pos] = (int)(r & 0xFFFFFFu);
  }
}

// ========== per-node relation gather (f32, sorted, 4 loads in flight) ==========
#define ACCUM(se, v)                                                         \
  {                                                                          \
    const int r_ = (se) & 3;                                                 \
    if (r_ == 0) { a0.x += v.x; a0.y += v.y; a0.z += v.z; a0.w += v.w; }     \
    else if (r_ == 1) { a1.x += v.x; a1.y += v.y; a1.z += v.z; a1.w += v.w; }\
    else if (r_ == 2) { a2.x += v.x; a2.y += v.y; a2.z += v.z; a2.w += v.w; }\
    else { a3.x += v.x; a3.y += v.y; a3.z += v.z; a3.w += v.w; }             \
  }

__global__ __launch_bounds__(256) void gather_rel(
    const float* __restrict__ h, const int* __restrict__ rowptr,
    const int* __restrict__ srcet, float* __restrict__ aggr, int N,
    int relu_in) {
  const int n = blockIdx.x * 4 + (threadIdx.x >> 6);
  const int lane = threadIdx.x & 63;
  const int g = lane >> 4;    // edge slot 0..3
  const int t = lane & 15;    // float4 chunk 0..15
  if (n >= N) return;
  const int beg = rowptr[n], end = rowptr[n + 1];

  float4 a0 = make_float4(0.f, 0.f, 0.f, 0.f);
  float4 a1 = a0, a2 = a0, a3 = a0;

  int j = beg + g;
  for (; j + 12 < end; j += 16) {
    const int se0 = srcet[j];
    const int se1 = srcet[j + 4];
    const int se2 = srcet[j + 8];
    const int se3 = srcet[j + 12];
    float4 v0 = *(const float4*)(h + ((size_t)(se0 >> 2) << 6) + (t << 2));
    float4 v1 = *(const float4*)(h + ((size_t)(se1 >> 2) << 6) + (t << 2));
    float4 v2 = *(const float4*)(h + ((size_t)(se2 >> 2) << 6) + (t << 2));
    float4 v3 = *(const float4*)(h + ((size_t)(se3 >> 2) << 6) + (t << 2));
    if (relu_in) {
      v0.x = fmaxf(v0.x, 0.f); v0.y = fmaxf(v0.y, 0.f);
      v0.z = fmaxf(v0.z, 0.f); v0.w = fmaxf(v0.w, 0.f);
      v1.x = fmaxf(v1.x, 0.f); v1.y = fmaxf(v1.y, 0.f);
      v1.z = fmaxf(v1.z, 0.f); v1.w = fmaxf(v1.w, 0.f);
      v2.x = fmaxf(v2.x, 0.f); v2.y = fmaxf(v2.y, 0.f);
      v2.z = fmaxf(v2.z, 0.f); v2.w = fmaxf(v2.w, 0.f);
      v3.x = fmaxf(v3.x, 0.f); v3.y = fmaxf(v3.y, 0.f);
      v3.z = fmaxf(v3.z, 0.f); v3.w = fmaxf(v3.w, 0.f);
    }
    ACCUM(se0, v0);
    ACCUM(se1, v1);
    ACCUM(se2, v2);
    ACCUM(se3, v3);
  }
  for (; j < end; j += 4) {
    const int se0 = srcet[j];
    float4 v0 = *(const float4*)(h + ((size_t)(se0 >> 2) << 6) + (t << 2));
    if (relu_in) {
      v0.x = fmaxf(v0.x, 0.f); v0.y = fmaxf(v0.y, 0.f);
      v0.z = fmaxf(v0.z, 0.f); v0.w = fmaxf(v0.w, 0.f);
    }
    ACCUM(se0, v0);
  }

#pragma unroll
  for (int off = 16; off <= 32; off <<= 1) {
    a0.x += __shfl_xor(a0.x, off); a0.y += __shfl_xor(a0.y, off);
    a0.z += __shfl_xor(a0.z, off); a0.w += __shfl_xor(a0.w, off);
    a1.x += __shfl_xor(a1.x, off); a1.y += __shfl_xor(a1.y, off);
    a1.z += __shfl_xor(a1.z, off); a1.w += __shfl_xor(a1.w, off);
    a2.x += __shfl_xor(a2.x, off); a2.y += __shfl_xor(a2.y, off);
    a2.z += __shfl_xor(a2.z, off); a2.w += __shfl_xor(a2.w, off);
    a3.x += __shfl_xor(a3.x, off); a3.y += __shfl_xor(a3.y, off);
    a3.z += __shfl_xor(a3.z, off); a3.w += __shfl_xor(a3.w, off);
  }

  const float4 res = (g == 0) ? a0 : (g == 1) ? a1 : (g == 2) ? a2 : a3;
  *(float4*)(aggr + ((size_t)n << 8) + (g << 6) + (t << 2)) = res;
}

// ================= dense: hnext = sum_r aggr[r]@Wrel[r] + relu?(h)@Wloop + brel ==========
__global__ __launch_bounds__(256) void rgcn_dense(
    const float* __restrict__ aggr, const float* __restrict__ hin,
    const float* __restrict__ Wrel, const float* __restrict__ Wloop,
    const float* __restrict__ brel, float* __restrict__ hnext, int N,
    int relu_in) {
  const int lane = threadIdx.x & 63;
  const int wv = threadIdx.x >> 6;
  const int c0 = __builtin_amdgcn_readfirstlane(wv << 4);
  const int n = blockIdx.x * 64 + lane;

  float acc[16];
#pragma unroll
  for (int jj = 0; jj < 16; ++jj) acc[jj] = brel[c0 + jj];

  float in[DD];
#pragma unroll 1
  for (int m = 0; m < 5; ++m) {
    const float* __restrict__ W =
        (m < 4) ? (Wrel + (size_t)m * DD * DD) : Wloop;
    if (n < N) {
      const float4* p = (m < 4)
                            ? (const float4*)(aggr + ((size_t)n << 8) + (m << 6))
                            : (const float4*)(hin + ((size_t)n << 6));
#pragma unroll
      for (int t = 0; t < DD / 4; ++t) {
        float4 v = p[t];
        if (m == 4 && relu_in) {
          v.x = fmaxf(v.x, 0.f); v.y = fmaxf(v.y, 0.f);
          v.z = fmaxf(v.z, 0.f); v.w = fmaxf(v.w, 0.f);
        }
        in[4 * t + 0] = v.x; in[4 * t + 1] = v.y;
        in[4 * t + 2] = v.z; in[4 * t + 3] = v.w;
      }
    } else {
#pragma unroll
      for (int t = 0; t < DD; ++t) in[t] = 0.f;
    }
#pragma unroll
    for (int k = 0; k < DD; ++k) {
      const float hk = in[k];
#pragma unroll
      for (int jj = 0; jj < 16; ++jj)
        acc[jj] = fmaf(hk, W[k * DD + c0 + jj], acc[jj]);
    }
  }
  if (n < N) {
    float* o = hnext + ((size_t)n << 6) + c0;
#pragma unroll
    for (int jj = 0; jj < 16; jj += 4)
      *(float4*)(o + jj) =
          make_float4(acc[jj], acc[jj + 1], acc[jj + 2], acc[jj + 3]);
  }
}

// ====== GAT projection: z = relu(h)@Wg, fused el/er + global max(el) ======
__global__ __launch_bounds__(256) void gemm_gat(
    const float* __restrict__ hin, const float* __restrict__ Wg,
    const float* __restrict__ al, const float* __restrict__ ar,
    float* __restrict__ z, float* __restrict__ el, float* __restrict__ er,
    unsigned* __restrict__ genc, int N) {
  __shared__ float sel[4][64];
  __shared__ float ser[4][64];
  const int lane = threadIdx.x & 63;
  const int wv = threadIdx.x >> 6;
  const int c0 = __builtin_amdgcn_readfirstlane(wv << 4);
  const int n = blockIdx.x * 64 + lane;

  float h[DD];
  if (n < N) {
    const float4* hp = (const float4*)(hin + (size_t)n * DD);
#pragma unroll
    for (int t = 0; t < DD / 4; ++t) {
      float4 v = hp[t];
      v.x = fmaxf(v.x, 0.f); v.y = fmaxf(v.y, 0.f);
      v.z = fmaxf(v.z, 0.f); v.w = fmaxf(v.w, 0.f);
      h[4 * t + 0] = v.x; h[4 * t + 1] = v.y;
      h[4 * t + 2] = v.z; h[4 * t + 3] = v.w;
    }
  } else {
#pragma unroll
    for (int t = 0; t < DD; ++t) h[t] = 0.f;
  }
  float acc[16];
#pragma unroll
  for (int j = 0; j < 16; ++j) acc[j] = 0.f;
#pragma unroll
  for (int k = 0; k < DD; ++k) {
    const float hk = h[k];
#pragma unroll
    for (int j = 0; j < 16; ++j)
      acc[j] = fmaf(hk, Wg[k * DD + c0 + j], acc[j]);
  }

  float pl = 0.f, pr = 0.f;
#pragma unroll
  for (int j = 0; j < 16; ++j) {
    pl = fmaf(acc[j], al[c0 + j], pl);
    pr = fmaf(acc[j], ar[c0 + j], pr);
  }
  sel[wv][lane] = pl;
  ser[wv][lane] = pr;

  if (n < N) {
    float* o = z + ((size_t)n << 6) + c0;
#pragma unroll
    for (int j = 0; j < 16; j += 4)
      *(float4*)(o + j) =
          make_float4(acc[j], acc[j + 1], acc[j + 2], acc[j + 3]);
  }
  __syncthreads();
  if (wv == 0) {
    float eln = sel[0][lane] + sel[1][lane] + sel[2][lane] + sel[3][lane];
    float ern = ser[0][lane] + ser[1][lane] + ser[2][lane] + ser[3][lane];
    if (n < N) {
      el[n] = eln;
      er[n] = ern;
    }
    float mx = (n < N) ? eln : -1e30f;
#pragma unroll
    for (int off = 32; off > 0; off >>= 1) mx = fmaxf(mx, __shfl_xor(mx, off));
    if (lane == 0) atomicMax(genc, enc_f32(mx));
  }
}

// ========= fused GAT aggregation, single pass (upper-bound max) =========
__global__ __launch_bounds__(256) void gat_fused(
    const float* __restrict__ z, const float* __restrict__ el,
    const float* __restrict__ er, const int* __restrict__ rowptr,
    const int* __restrict__ srcet, const unsigned* __restrict__ genc,
    float* __restrict__ hg, int N) {
  const int n = blockIdx.x * 4 + (threadIdx.x >> 6);
  const int lane = threadIdx.x & 63;
  const int g = lane >> 4;
  const int t = lane & 15;
  if (n >= N) return;
  const int beg = rowptr[n], end = rowptr[n + 1];
  const float ern = er[n];
  // upper bound on leaky(el[s]+ern): leaky is monotone
  float mb = dec_f32(*genc) + ern;
  mb = (mb > 0.f) ? mb : 0.2f * mb;

  float4 num = make_float4(0.f, 0.f, 0.f, 0.f);
  float den = 0.f;
  for (int j = beg + g; j < end; j += 4) {
    const int se = srcet[j];
    const int s = se >> 2;
    float x = el[s] + ern;
    x = (x > 0.f) ? x : 0.2f * x;
    const float w = __expf(x - mb);
    den += w;
    float4 v = *(const float4*)(z + ((size_t)s << 6) + (t << 2));
    num.x = fmaf(w, v.x, num.x);
    num.y = fmaf(w, v.y, num.y);
    num.z = fmaf(w, v.z, num.z);
    num.w = fmaf(w, v.w, num.w);
  }
  // sum the 4 lane-groups (each edge counted exactly once per fixed t)
#pragma unroll
  for (int off = 16; off <= 32; off <<= 1) {
    num.x += __shfl_xor(num.x, off);
    num.y += __shfl_xor(num.y, off);
    num.z += __shfl_xor(num.z, off);
    num.w += __shfl_xor(num.w, off);
    den += __shfl_xor(den, off);
  }
  if (g == 0) {
    const float inv = 1.f / fmaxf(den, 1e-9f);
    float4 o = make_float4(num.x * inv, num.y * inv, num.z * inv, num.w * inv);
    *(float4*)(hg + ((size_t)n << 6) + (t << 2)) = o;
  }
}

// ================= pooled head, two-level =================
__global__ __launch_bounds__(256) void pool_head2(
    const float* __restrict__ hg, const float* __restrict__ Wd,
    const int* __restrict__ gids, float* __restrict__ out, int N, int B) {
  __shared__ float acc[1024];
  for (int i = threadIdx.x; i < B; i += 256) acc[i] = 0.f;
  __syncthreads();

  const int wv = threadIdx.x >> 6;
  const int lane = threadIdx.x & 63;
  const int sub = lane & 3;
  const int idx = lane >> 2;

  const float4 w0 = *(const float4*)(Wd + (sub << 4) + 0);
  const float4 w1 = *(const float4*)(Wd + (sub << 4) + 4);
  const float4 w2 = *(const float4*)(Wd + (sub << 4) + 8);
  const float4 w3 = *(const float4*)(Wd + (sub << 4) + 12);

  const int base0 = blockIdx.x * POOL_NPB;
#pragma unroll 1
  for (int it = 0; it < POOL_NPB / 64; ++it) {
    const int n = base0 + it * 64 + wv * 16 + idx;
    if (n < N) {
      const float* p = hg + ((size_t)n << 6) + (sub << 4);
      const float4 v0 = *(const float4*)(p + 0);
      const float4 v1 = *(const float4*)(p + 4);
      const float4 v2 = *(const float4*)(p + 8);
      const float4 v3 = *(const float4*)(p + 12);
      float s = v0.x * w0.x + v0.y * w0.y + v0.z * w0.z + v0.w * w0.w;
      s = fmaf(v1.x, w1.x, s); s = fmaf(v1.y, w1.y, s);
      s = fmaf(v1.z, w1.z, s); s = fmaf(v1.w, w1.w, s);
      s = fmaf(v2.x, w2.x, s); s = fmaf(v2.y, w2.y, s);
      s = fmaf(v2.z, w2.z, s); s = fmaf(v2.w, w2.w, s);
      s = fmaf(v3.x, w3.x, s); s = fmaf(v3.y, w3.y, s);
      s = fmaf(v3.z, w3.z, s); s = fmaf(v3.w, w3.w, s);
      s += __shfl_xor(s, 1);
      s += __shfl_xor(s, 2);
      if (sub == 0) atomicAdd(&acc[gids[n]], s);
    }
  }
  __syncthreads();
  for (int i = threadIdx.x; i < B; i += 256) {
    const float v = acc[i];
    if (v != 0.f) unsafeAtomicAdd(out + i, v);
  }
}

__global__ void init_out_k(float* out, const float* bd, int n,
                           unsigned* genc) {
  int i = blockIdx.x * blockDim.x + threadIdx.x;
  if (i < n) out[i] = bd[0];
  if (i == 0) *genc = enc_f32(-1e30f);
}

// ================= launch =================
extern "C" void kernel_launch(void* const* d_in, const int* in_sizes, int n_in,
                              void* d_out, int out_size, void* d_ws,
                              size_t ws_size, hipStream_t stream) {
  const float* h0 = (const float*)d_in[0];
  const float* Wrel = (const float*)d_in[1];
  const float* Wloop = (const float*)d_in[2];
  const float* brel = (const float*)d_in[3];
  const float* Wg = (const float*)d_in[4];
  const float* al = (const float*)d_in[5];
  const float* ar = (const float*)d_in[6];
  const float* Wd = (const float*)d_in[7];
  const float* bd = (const float*)d_in[8];
  const int* src = (const int*)d_in[9];
  const int* dst = (const int*)d_in[10];
  const int* et = (const int*)d_in[11];
  const int* gids = (const int*)d_in[12];

  const int N = in_sizes[0] / DD;
  const int E = in_sizes[9];
  const int L = in_sizes[2] / (DD * DD);
  float* out = (float*)d_out;

  // ---- workspace layout ----
  float* wsf = (float*)d_ws;
  float* hA = wsf;                          // N*64
  float* hB = hA + (size_t)N * DD;          // N*64
  float* aggr = hB + (size_t)N * DD;        // N*256
  int* rowptr = (int*)(aggr + (size_t)N * 4 * DD);  // N+1
  int* srcet = rowptr + N + 1;              // E
  float* el = (float*)(srcet + E);          // N
  float* er = el + N;                       // N
  int* chist = (int*)(er + N);              // 256
  int* gcur = chist + 256;                  // 256
  int* cbase = gcur + 256;                  // 256
  unsigned* genc = (unsigned*)(cbase + 256);  // 1
  unsigned* staging = (unsigned*)aggr;      // E uint, overlays aggr
  float* hg = aggr;                         // overlay after last dense

  dim3 b256(256);
  const int grid_dense = (N + 63) / 64;
  const int grid_n4 = (N + 3) / 4;
  const int nfb = (E + EPB - 1) / EPB;
  const int ncb = (N + 255) >> 8;

  hipLaunchKernelGGL(init_out_k, dim3((out_size + 255) / 256), b256, 0, stream,
                     out, bd, out_size, genc);

  // ---- CSR build (hierarchical fill, (dst,rel)-sorted output) ----
  hipMemsetAsync(chist, 0, 256 * 4, stream);
  hipLaunchKernelGGL(k_hist, dim3(nfb), b256, 0, stream, dst, chist, E);
  hipLaunchKernelGGL(cscan, dim3(1), b256, 0, stream, chist, gcur, cbase);
  hipLaunchKernelGGL(f2_coarse, dim3(nfb), b256, 0, stream, src, dst, et, gcur,
                     staging, E);
  hipLaunchKernelGGL(f3_fine3, dim3(ncb), dim3(1024), 0, stream, staging, cbase,
                     rowptr, srcet, N, E, ncb);

  // ---- RGCN layers ----
  const float* cur = h0;
  float* nxt = hA;
  for (int l = 0; l < L; ++l) {
    hipLaunchKernelGGL(gather_rel, dim3(grid_n4), b256, 0, stream, cur, rowptr,
                       srcet, aggr, N, l > 0 ? 1 : 0);
    hipLaunchKernelGGL(rgcn_dense, dim3(grid_dense), b256, 0, stream, aggr, cur,
                       Wrel + (size_t)l * 4 * DD * DD,
                       Wloop + (size_t)l * DD * DD, brel + (size_t)l * DD, nxt,
                       N, l > 0 ? 1 : 0);
    cur = nxt;
    nxt = (cur == hA) ? hB : hA;
  }

  // ---- GAT ----
  float* zb = nxt;
  hipLaunchKernelGGL(gemm_gat, dim3(grid_dense), b256, 0, stream, cur, Wg, al,
                     ar, zb, el, er, genc, N);
  hipLaunchKernelGGL(gat_fused, dim3(grid_n4), b256, 0, stream, zb, el, er,
                     rowptr, srcet, genc, hg, N);

  const int grid_pool = (N + POOL_NPB - 1) / POOL_NPB;
  hipLaunchKernelGGL(pool_head2, dim3(grid_pool), b256, 0, stream, hg, Wd, gids,
                     out, N, out_size);
}

// Round 13
// 645.840 us; speedup vs baseline: 1.3588x; 1.0848x over previous
//
#include <hip/hip_runtime.h>

#define DD 64
#define POOL_NPB 512
#define EPB 1024  // edges per block in fill pipeline

__device__ __forceinline__ unsigned enc_f32(float x) {
  unsigned u = __float_as_uint(x);
  return (u & 0x80000000u) ? ~u : (u | 0x80000000u);
}
__device__ __forceinline__ float dec_f32(unsigned k) {
  return (k & 0x80000000u) ? __uint_as_float(k ^ 0x80000000u)
                           : __uint_as_float(~k);
}

// ================= coarse histogram (LDS only) =================
__global__ __launch_bounds__(256) void k_hist(const int* __restrict__ dst,
                                              int* __restrict__ chist, int E) {
  __shared__ int lh[256];
  lh[threadIdx.x] = 0;
  __syncthreads();
  const int base = blockIdx.x * EPB;
#pragma unroll
  for (int k = 0; k < EPB / 256; ++k) {
    const int e = base + k * 256 + threadIdx.x;
    if (e < E) atomicAdd(&lh[dst[e] >> 8], 1);
  }
  __syncthreads();
  const int v = lh[threadIdx.x];
  if (v) atomicAdd(&chist[threadIdx.x], v);
}

// ---- scan of coarse histogram -> gcur (mutable) + cbase (stable) ----
__global__ __launch_bounds__(256) void cscan(const int* __restrict__ chist,
                                             int* __restrict__ gcur,
                                             int* __restrict__ cbase) {
  __shared__ int s[256];
  const int t = threadIdx.x;
  const int v = chist[t];
  s[t] = v;
  __syncthreads();
#pragma unroll
  for (int off = 1; off < 256; off <<= 1) {
    const int add = (t >= off) ? s[t - off] : 0;
    __syncthreads();
    s[t] += add;
    __syncthreads();
  }
  const int ex = s[t] - v;
  gcur[t] = ex;
  cbase[t] = ex;
}

// ---- coarse scatter: LDS-reordered, bucket-contiguous 4B packed records ----
__global__ __launch_bounds__(256) void f2_coarse(
    const int* __restrict__ src, const int* __restrict__ dst,
    const int* __restrict__ et, int* __restrict__ gcur,
    unsigned* __restrict__ staging, int E) {
  __shared__ int lcnt[256];
  __shared__ int sc[256];
  __shared__ int lbase[256];
  __shared__ int gb[256];
  __shared__ unsigned rec[EPB];
  __shared__ unsigned char rbk[EPB];

  const int t = threadIdx.x;
  const int base = blockIdx.x * EPB;
  const int bc = min(EPB, E - base);

  lcnt[t] = 0;
  __syncthreads();

  int d_[EPB / 256], se_[EPB / 256], rk_[EPB / 256];
#pragma unroll
  for (int k = 0; k < EPB / 256; ++k) {
    const int e = base + k * 256 + t;
    if (e < E) {
      const int d = dst[e];
      d_[k] = d;
      se_[k] = (src[e] << 2) | et[e];
      rk_[k] = atomicAdd(&lcnt[d >> 8], 1);
    } else {
      d_[k] = -1;
    }
  }
  __syncthreads();

  const int lv = lcnt[t];
  sc[t] = lv;
  __syncthreads();
#pragma unroll
  for (int off = 1; off < 256; off <<= 1) {
    const int add = (t >= off) ? sc[t - off] : 0;
    __syncthreads();
    sc[t] += add;
    __syncthreads();
  }
  lbase[t] = sc[t] - lv;
  gb[t] = lv ? atomicAdd(&gcur[t], lv) : 0;
  __syncthreads();

#pragma unroll
  for (int k = 0; k < EPB / 256; ++k) {
    if (d_[k] >= 0) {
      const int cb = d_[k] >> 8;
      const int pos = lbase[cb] + rk_[k];
      rec[pos] = ((unsigned)(d_[k] & 255) << 24) | (unsigned)se_[k];
      rbk[pos] = (unsigned char)cb;
    }
  }
  __syncthreads();

  for (int idx = t; idx < bc; idx += 256) {
    const int cb = rbk[idx];
    staging[gb[cb] + (idx - lbase[cb])] = rec[idx];
  }
}

// ---- fine placement, 1024 bins = (d&255)*4 + rel: (dst,rel)-sorted ----
__global__ __launch_bounds__(1024) void f3_fine3(
    const unsigned* __restrict__ staging, const int* __restrict__ cbase,
    int* __restrict__ rowptr, int* __restrict__ srcet, int N, int E, int ncb) {
  __shared__ int ldeg[1024];
  __shared__ int sc[1024];
  __shared__ int lcur[1024];
  const int cb = blockIdx.x;
  const int t = threadIdx.x;
  const int s0 = cbase[cb];
  const int s1 = (cb + 1 < ncb) ? cbase[cb + 1] : E;

  ldeg[t] = 0;
  __syncthreads();
  for (int i = s0 + t; i < s1; i += 1024) {
    const unsigned r = staging[i];
    atomicAdd(&ldeg[((r >> 24) << 2) | (r & 3u)], 1);
  }
  __syncthreads();

  const int v = ldeg[t];
  sc[t] = v;
  __syncthreads();
#pragma unroll
  for (int off = 1; off < 1024; off <<= 1) {
    const int add = (t >= off) ? sc[t - off] : 0;
    __syncthreads();
    sc[t] += add;
    __syncthreads();
  }
  const int base = s0 + sc[t] - v;
  lcur[t] = base;
  if ((t & 3) == 0) {
    const int dn = (cb << 8) + (t >> 2);
    if (dn < N) rowptr[dn] = base;
  }
  if (cb == ncb - 1 && t == 0) rowptr[N] = E;
  __syncthreads();

  for (int i = s0 + t; i < s1; i += 1024) {
    const unsigned r = staging[i];
    const int pos = atomicAdd(&lcur[((r >> 24) << 2) | (r & 3u)], 1);
    srcet[pos] = (int)(r & 0xFFFFFFu);
  }
}

// ========== per-node relation gather (f32, sorted, 4 loads in flight) ==========
// h rows are already relu'd (dense stores post-relu); h0 enters raw (correct).
#define ACCUM(se, v)                                                         \
  {                                                                          \
    const int r_ = (se) & 3;                                                 \
    if (r_ == 0) { a0.x += v.x; a0.y += v.y; a0.z += v.z; a0.w += v.w; }     \
    else if (r_ == 1) { a1.x += v.x; a1.y += v.y; a1.z += v.z; a1.w += v.w; }\
    else if (r_ == 2) { a2.x += v.x; a2.y += v.y; a2.z += v.z; a2.w += v.w; }\
    else { a3.x += v.x; a3.y += v.y; a3.z += v.z; a3.w += v.w; }             \
  }

__global__ __launch_bounds__(256) void gather_rel(
    const float* __restrict__ h, const int* __restrict__ rowptr,
    const int* __restrict__ srcet, float* __restrict__ aggr, int N) {
  const int n = blockIdx.x * 4 + (threadIdx.x >> 6);
  const int lane = threadIdx.x & 63;
  const int g = lane >> 4;    // edge slot 0..3
  const int t = lane & 15;    // float4 chunk 0..15
  if (n >= N) return;
  const int beg = rowptr[n], end = rowptr[n + 1];

  float4 a0 = make_float4(0.f, 0.f, 0.f, 0.f);
  float4 a1 = a0, a2 = a0, a3 = a0;

  int j = beg + g;
  for (; j + 12 < end; j += 16) {
    const int se0 = srcet[j];
    const int se1 = srcet[j + 4];
    const int se2 = srcet[j + 8];
    const int se3 = srcet[j + 12];
    float4 v0 = *(const float4*)(h + ((size_t)(se0 >> 2) << 6) + (t << 2));
    float4 v1 = *(const float4*)(h + ((size_t)(se1 >> 2) << 6) + (t << 2));
    float4 v2 = *(const float4*)(h + ((size_t)(se2 >> 2) << 6) + (t << 2));
    float4 v3 = *(const float4*)(h + ((size_t)(se3 >> 2) << 6) + (t << 2));
    ACCUM(se0, v0);
    ACCUM(se1, v1);
    ACCUM(se2, v2);
    ACCUM(se3, v3);
  }
  for (; j < end; j += 4) {
    const int se0 = srcet[j];
    float4 v0 = *(const float4*)(h + ((size_t)(se0 >> 2) << 6) + (t << 2));
    ACCUM(se0, v0);
  }

#pragma unroll
  for (int off = 16; off <= 32; off <<= 1) {
    a0.x += __shfl_xor(a0.x, off); a0.y += __shfl_xor(a0.y, off);
    a0.z += __shfl_xor(a0.z, off); a0.w += __shfl_xor(a0.w, off);
    a1.x += __shfl_xor(a1.x, off); a1.y += __shfl_xor(a1.y, off);
    a1.z += __shfl_xor(a1.z, off); a1.w += __shfl_xor(a1.w, off);
    a2.x += __shfl_xor(a2.x, off); a2.y += __shfl_xor(a2.y, off);
    a2.z += __shfl_xor(a2.z, off); a2.w += __shfl_xor(a2.w, off);
    a3.x += __shfl_xor(a3.x, off); a3.y += __shfl_xor(a3.y, off);
    a3.z += __shfl_xor(a3.z, off); a3.w += __shfl_xor(a3.w, off);
  }

  const float4 res = (g == 0) ? a0 : (g == 1) ? a1 : (g == 2) ? a2 : a3;
  *(float4*)(aggr + ((size_t)n << 8) + (g << 6) + (t << 2)) = res;
}

// ===== dense (LDS-tiled): hnext = relu(sum_r aggr[r]@Wrel[r] + hin@Wloop + brel) =====
// Coalesced global<->LDS staging; stride-65 LDS rows (conflict-free).
__global__ __launch_bounds__(256) void rgcn_dense_t(
    const float* __restrict__ aggr, const float* __restrict__ hin,
    const float* __restrict__ Wrel, const float* __restrict__ Wloop,
    const float* __restrict__ brel, float* __restrict__ hnext, int N) {
  __shared__ float tile[64 * 65];
  const int tid = threadIdx.x;
  const int lane = tid & 63;
  const int wv = tid >> 6;
  const int c0 = __builtin_amdgcn_readfirstlane(wv << 4);
  const int n0 = blockIdx.x * 64;

  float acc[16];
#pragma unroll
  for (int jj = 0; jj < 16; ++jj) acc[jj] = brel[c0 + jj];

#pragma unroll 1
  for (int m = 0; m < 5; ++m) {
    __syncthreads();  // tile free (previous compute done)
#pragma unroll
    for (int q = 0; q < 4; ++q) {
      const int f = q * 256 + tid;
      const int row = f >> 4;
      const int c4 = (f & 15) << 2;
      const int nn = n0 + row;
      float4 v = make_float4(0.f, 0.f, 0.f, 0.f);
      if (nn < N) {
        const float* s = (m < 4) ? (aggr + ((size_t)nn << 8) + (m << 6) + c4)
                                 : (hin + ((size_t)nn << 6) + c4);
        v = *(const float4*)s;
      }
      float* d = tile + row * 65 + c4;
      d[0] = v.x; d[1] = v.y; d[2] = v.z; d[3] = v.w;
    }
    __syncthreads();
    const float* __restrict__ W =
        (m < 4) ? (Wrel + (size_t)m * DD * DD) : Wloop;
    const float* trow = tile + lane * 65;
#pragma unroll
    for (int k = 0; k < DD; ++k) {
      const float hk = trow[k];
#pragma unroll
      for (int jj = 0; jj < 16; ++jj)
        acc[jj] = fmaf(hk, W[k * DD + c0 + jj], acc[jj]);
    }
  }

  // write-out via LDS (relu fused), coalesced
  __syncthreads();
  {
    float* d = tile + lane * 65 + c0;
#pragma unroll
    for (int jj = 0; jj < 16; ++jj) d[jj] = fmaxf(acc[jj], 0.f);
  }
  __syncthreads();
#pragma unroll
  for (int q = 0; q < 4; ++q) {
    const int f = q * 256 + tid;
    const int row = f >> 4;
    const int c4 = (f & 15) << 2;
    const int nn = n0 + row;
    if (nn < N) {
      const float* s = tile + row * 65 + c4;
      *(float4*)(hnext + ((size_t)nn << 6) + c4) =
          make_float4(s[0], s[1], s[2], s[3]);
    }
  }
}

// ===== GAT projection (LDS-tiled): z = h@Wg (h already relu'd), el/er + gmax =====
__global__ __launch_bounds__(256) void gemm_gat_t(
    const float* __restrict__ hin, const float* __restrict__ Wg,
    const float* __restrict__ al, const float* __restrict__ ar,
    float* __restrict__ z, float* __restrict__ el, float* __restrict__ er,
    unsigned* __restrict__ genc, int N) {
  __shared__ float tile[64 * 65];
  __shared__ float sel[4][64];
  __shared__ float ser[4][64];
  const int tid = threadIdx.x;
  const int lane = tid & 63;
  const int wv = tid >> 6;
  const int c0 = __builtin_amdgcn_readfirstlane(wv << 4);
  const int n0 = blockIdx.x * 64;
  const int n = n0 + lane;

#pragma unroll
  for (int q = 0; q < 4; ++q) {
    const int f = q * 256 + tid;
    const int row = f >> 4;
    const int c4 = (f & 15) << 2;
    const int nn = n0 + row;
    float4 v = make_float4(0.f, 0.f, 0.f, 0.f);
    if (nn < N) v = *(const float4*)(hin + ((size_t)nn << 6) + c4);
    float* d = tile + row * 65 + c4;
    d[0] = v.x; d[1] = v.y; d[2] = v.z; d[3] = v.w;
  }
  __syncthreads();

  float acc[16];
#pragma unroll
  for (int jj = 0; jj < 16; ++jj) acc[jj] = 0.f;
  {
    const float* trow = tile + lane * 65;
#pragma unroll
    for (int k = 0; k < DD; ++k) {
      const float hk = trow[k];
#pragma unroll
      for (int jj = 0; jj < 16; ++jj)
        acc[jj] = fmaf(hk, Wg[k * DD + c0 + jj], acc[jj]);
    }
  }

  float pl = 0.f, pr = 0.f;
#pragma unroll
  for (int jj = 0; jj < 16; ++jj) {
    pl = fmaf(acc[jj], al[c0 + jj], pl);
    pr = fmaf(acc[jj], ar[c0 + jj], pr);
  }
  sel[wv][lane] = pl;
  ser[wv][lane] = pr;

  // z via LDS, coalesced
  __syncthreads();
  {
    float* d = tile + lane * 65 + c0;
#pragma unroll
    for (int jj = 0; jj < 16; ++jj) d[jj] = acc[jj];
  }
  __syncthreads();
#pragma unroll
  for (int q = 0; q < 4; ++q) {
    const int f = q * 256 + tid;
    const int row = f >> 4;
    const int c4 = (f & 15) << 2;
    const int nn = n0 + row;
    if (nn < N) {
      const float* s = tile + row * 65 + c4;
      *(float4*)(z + ((size_t)nn << 6) + c4) =
          make_float4(s[0], s[1], s[2], s[3]);
    }
  }
  if (wv == 0) {
    float eln = sel[0][lane] + sel[1][lane] + sel[2][lane] + sel[3][lane];
    float ern = ser[0][lane] + ser[1][lane] + ser[2][lane] + ser[3][lane];
    if (n < N) {
      el[n] = eln;
      er[n] = ern;
    }
    float mx = (n < N) ? eln : -1e30f;
#pragma unroll
    for (int off = 32; off > 0; off >>= 1) mx = fmaxf(mx, __shfl_xor(mx, off));
    if (lane == 0) atomicMax(genc, enc_f32(mx));
  }
}

// ========= fused GAT aggregation, single pass (upper-bound max) =========
__global__ __launch_bounds__(256) void gat_fused(
    const float* __restrict__ z, const float* __restrict__ el,
    const float* __restrict__ er, const int* __restrict__ rowptr,
    const int* __restrict__ srcet, const unsigned* __restrict__ genc,
    float* __restrict__ hg, int N) {
  const int n = blockIdx.x * 4 + (threadIdx.x >> 6);
  const int lane = threadIdx.x & 63;
  const int g = lane >> 4;
  const int t = lane & 15;
  if (n >= N) return;
  const int beg = rowptr[n], end = rowptr[n + 1];
  const float ern = er[n];
  float mb = dec_f32(*genc) + ern;
  mb = (mb > 0.f) ? mb : 0.2f * mb;

  float4 num = make_float4(0.f, 0.f, 0.f, 0.f);
  float den = 0.f;
  for (int j = beg + g; j < end; j += 4) {
    const int se = srcet[j];
    const int s = se >> 2;
    float x = el[s] + ern;
    x = (x > 0.f) ? x : 0.2f * x;
    const float w = __expf(x - mb);
    den += w;
    float4 v = *(const float4*)(z + ((size_t)s << 6) + (t << 2));
    num.x = fmaf(w, v.x, num.x);
    num.y = fmaf(w, v.y, num.y);
    num.z = fmaf(w, v.z, num.z);
    num.w = fmaf(w, v.w, num.w);
  }
#pragma unroll
  for (int off = 16; off <= 32; off <<= 1) {
    num.x += __shfl_xor(num.x, off);
    num.y += __shfl_xor(num.y, off);
    num.z += __shfl_xor(num.z, off);
    num.w += __shfl_xor(num.w, off);
    den += __shfl_xor(den, off);
  }
  if (g == 0) {
    const float inv = 1.f / fmaxf(den, 1e-9f);
    float4 o = make_float4(num.x * inv, num.y * inv, num.z * inv, num.w * inv);
    *(float4*)(hg + ((size_t)n << 6) + (t << 2)) = o;
  }
}

// ================= pooled head, two-level =================
__global__ __launch_bounds__(256) void pool_head2(
    const float* __restrict__ hg, const float* __restrict__ Wd,
    const int* __restrict__ gids, float* __restrict__ out, int N, int B) {
  __shared__ float acc[1024];
  for (int i = threadIdx.x; i < B; i += 256) acc[i] = 0.f;
  __syncthreads();

  const int wv = threadIdx.x >> 6;
  const int lane = threadIdx.x & 63;
  const int sub = lane & 3;
  const int idx = lane >> 2;

  const float4 w0 = *(const float4*)(Wd + (sub << 4) + 0);
  const float4 w1 = *(const float4*)(Wd + (sub << 4) + 4);
  const float4 w2 = *(const float4*)(Wd + (sub << 4) + 8);
  const float4 w3 = *(const float4*)(Wd + (sub << 4) + 12);

  const int base0 = blockIdx.x * POOL_NPB;
#pragma unroll 1
  for (int it = 0; it < POOL_NPB / 64; ++it) {
    const int n = base0 + it * 64 + wv * 16 + idx;
    if (n < N) {
      const float* p = hg + ((size_t)n << 6) + (sub << 4);
      const float4 v0 = *(const float4*)(p + 0);
      const float4 v1 = *(const float4*)(p + 4);
      const float4 v2 = *(const float4*)(p + 8);
      const float4 v3 = *(const float4*)(p + 12);
      float s = v0.x * w0.x + v0.y * w0.y + v0.z * w0.z + v0.w * w0.w;
      s = fmaf(v1.x, w1.x, s); s = fmaf(v1.y, w1.y, s);
      s = fmaf(v1.z, w1.z, s); s = fmaf(v1.w, w1.w, s);
      s = fmaf(v2.x, w2.x, s); s = fmaf(v2.y, w2.y, s);
      s = fmaf(v2.z, w2.z, s); s = fmaf(v2.w, w2.w, s);
      s = fmaf(v3.x, w3.x, s); s = fmaf(v3.y, w3.y, s);
      s = fmaf(v3.z, w3.z, s); s = fmaf(v3.w, w3.w, s);
      s += __shfl_xor(s, 1);
      s += __shfl_xor(s, 2);
      if (sub == 0) atomicAdd(&acc[gids[n]], s);
    }
  }
  __syncthreads();
  for (int i = threadIdx.x; i < B; i += 256) {
    const float v = acc[i];
    if (v != 0.f) unsafeAtomicAdd(out + i, v);
  }
}

__global__ void init_out_k(float* out, const float* bd, int n,
                           unsigned* genc) {
  int i = blockIdx.x * blockDim.x + threadIdx.x;
  if (i < n) out[i] = bd[0];
  if (i == 0) *genc = enc_f32(-1e30f);
}

// ================= launch =================
extern "C" void kernel_launch(void* const* d_in, const int* in_sizes, int n_in,
                              void* d_out, int out_size, void* d_ws,
                              size_t ws_size, hipStream_t stream) {
  const float* h0 = (const float*)d_in[0];
  const float* Wrel = (const float*)d_in[1];
  const float* Wloop = (const float*)d_in[2];
  const float* brel = (const float*)d_in[3];
  const float* Wg = (const float*)d_in[4];
  const float* al = (const float*)d_in[5];
  const float* ar = (const float*)d_in[6];
  const float* Wd = (const float*)d_in[7];
  const float* bd = (const float*)d_in[8];
  const int* src = (const int*)d_in[9];
  const int* dst = (const int*)d_in[10];
  const int* et = (const int*)d_in[11];
  const int* gids = (const int*)d_in[12];

  const int N = in_sizes[0] / DD;
  const int E = in_sizes[9];
  const int L = in_sizes[2] / (DD * DD);
  float* out = (float*)d_out;

  // ---- workspace layout ----
  float* wsf = (float*)d_ws;
  float* hA = wsf;                          // N*64
  float* hB = hA + (size_t)N * DD;          // N*64
  float* aggr = hB + (size_t)N * DD;        // N*256
  int* rowptr = (int*)(aggr + (size_t)N * 4 * DD);  // N+1
  int* srcet = rowptr + N + 1;              // E
  float* el = (float*)(srcet + E);          // N
  float* er = el + N;                       // N
  int* chist = (int*)(er + N);              // 256
  int* gcur = chist + 256;                  // 256
  int* cbase = gcur + 256;                  // 256
  unsigned* genc = (unsigned*)(cbase + 256);  // 1
  unsigned* staging = (unsigned*)aggr;      // E uint, overlays aggr
  float* hg = aggr;                         // overlay after last dense

  dim3 b256(256);
  const int grid_dense = (N + 63) / 64;
  const int grid_n4 = (N + 3) / 4;
  const int nfb = (E + EPB - 1) / EPB;
  const int ncb = (N + 255) >> 8;

  hipLaunchKernelGGL(init_out_k, dim3((out_size + 255) / 256), b256, 0, stream,
                     out, bd, out_size, genc);

  // ---- CSR build (hierarchical fill, (dst,rel)-sorted output) ----
  hipMemsetAsync(chist, 0, 256 * 4, stream);
  hipLaunchKernelGGL(k_hist, dim3(nfb), b256, 0, stream, dst, chist, E);
  hipLaunchKernelGGL(cscan, dim3(1), b256, 0, stream, chist, gcur, cbase);
  hipLaunchKernelGGL(f2_coarse, dim3(nfb), b256, 0, stream, src, dst, et, gcur,
                     staging, E);
  hipLaunchKernelGGL(f3_fine3, dim3(ncb), dim3(1024), 0, stream, staging, cbase,
                     rowptr, srcet, N, E, ncb);

  // ---- RGCN layers (dense stores post-relu h) ----
  const float* cur = h0;
  float* nxt = hA;
  for (int l = 0; l < L; ++l) {
    hipLaunchKernelGGL(gather_rel, dim3(grid_n4), b256, 0, stream, cur, rowptr,
                       srcet, aggr, N);
    hipLaunchKernelGGL(rgcn_dense_t, dim3(grid_dense), b256, 0, stream, aggr,
                       cur, Wrel + (size_t)l * 4 * DD * DD,
                       Wloop + (size_t)l * DD * DD, brel + (size_t)l * DD, nxt,
                       N);
    cur = nxt;
    nxt = (cur == hA) ? hB : hA;
  }

  // ---- GAT ----
  float* zb = nxt;
  hipLaunchKernelGGL(gemm_gat_t, dim3(grid_dense), b256, 0, stream, cur, Wg, al,
                     ar, zb, el, er, genc, N);
  hipLaunchKernelGGL(gat_fused, dim3(grid_n4), b256, 0, stream, zb, el, er,
                     rowptr, srcet, genc, hg, N);

  const int grid_pool = (N + POOL_NPB - 1) / POOL_NPB;
  hipLaunchKernelGGL(pool_head2, dim3(grid_pool), b256, 0, stream, hg, Wd, gids,
                     out, N, out_size);
}

// Round 14
// 585.885 us; speedup vs baseline: 1.4978x; 1.1023x over previous
//
#include <hip/hip_runtime.h>

#define DD 64
#define POOL_NPB 512
#define EPB 1024  // edges per block in fill pipeline

__device__ __forceinline__ unsigned enc_f32(float x) {
  unsigned u = __float_as_uint(x);
  return (u & 0x80000000u) ? ~u : (u | 0x80000000u);
}
__device__ __forceinline__ float dec_f32(unsigned k) {
  return (k & 0x80000000u) ? __uint_as_float(k ^ 0x80000000u)
                           : __uint_as_float(~k);
}
__device__ __forceinline__ unsigned f2bf(float x) {
  unsigned u = __float_as_uint(x);
  return (u + 0x7fffu + ((u >> 16) & 1u)) >> 16;
}
__device__ __forceinline__ void unpack8(const uint4 raw, float* v) {
  v[0] = __uint_as_float(raw.x << 16);
  v[1] = __uint_as_float(raw.x & 0xffff0000u);
  v[2] = __uint_as_float(raw.y << 16);
  v[3] = __uint_as_float(raw.y & 0xffff0000u);
  v[4] = __uint_as_float(raw.z << 16);
  v[5] = __uint_as_float(raw.z & 0xffff0000u);
  v[6] = __uint_as_float(raw.w << 16);
  v[7] = __uint_as_float(raw.w & 0xffff0000u);
}

// ---- coarse scatter: LDS-reordered, fixed-capacity bucket runs (4B records) ----
// record = (d & 255) << 24 | se   (se = (src<<2)|et < 2^18)
__global__ __launch_bounds__(256) void f2_coarse(
    const int* __restrict__ src, const int* __restrict__ dst,
    const int* __restrict__ et, int* __restrict__ gcur,
    unsigned* __restrict__ staging, int E) {
  __shared__ int lcnt[256];
  __shared__ int sc[256];
  __shared__ int lbase[256];
  __shared__ int gb[256];
  __shared__ unsigned rec[EPB];
  __shared__ unsigned char rbk[EPB];

  const int t = threadIdx.x;
  const int base = blockIdx.x * EPB;
  const int bc = min(EPB, E - base);

  lcnt[t] = 0;
  __syncthreads();

  int d_[EPB / 256], se_[EPB / 256], rk_[EPB / 256];
#pragma unroll
  for (int k = 0; k < EPB / 256; ++k) {
    const int e = base + k * 256 + t;
    if (e < E) {
      const int d = dst[e];
      d_[k] = d;
      se_[k] = (src[e] << 2) | et[e];
      rk_[k] = atomicAdd(&lcnt[d >> 8], 1);
    } else {
      d_[k] = -1;
    }
  }
  __syncthreads();

  const int lv = lcnt[t];
  sc[t] = lv;
  __syncthreads();
#pragma unroll
  for (int off = 1; off < 256; off <<= 1) {
    const int add = (t >= off) ? sc[t - off] : 0;
    __syncthreads();
    sc[t] += add;
    __syncthreads();
  }
  lbase[t] = sc[t] - lv;
  gb[t] = lv ? atomicAdd(&gcur[t], lv) : 0;
  __syncthreads();

#pragma unroll
  for (int k = 0; k < EPB / 256; ++k) {
    if (d_[k] >= 0) {
      const int cb = d_[k] >> 8;
      const int pos = lbase[cb] + rk_[k];
      rec[pos] = ((unsigned)(d_[k] & 255) << 24) | (unsigned)se_[k];
      rbk[pos] = (unsigned char)cb;
    }
  }
  __syncthreads();

  for (int idx = t; idx < bc; idx += 256) {
    const int cb = rbk[idx];
    staging[gb[cb] + (idx - lbase[cb])] = rec[idx];
  }
}

// ---- scan bucket counts (from gcur) -> cbase; set rowptr[N] ----
__global__ __launch_bounds__(256) void cscan2(const int* __restrict__ gcur,
                                              int* __restrict__ cbase,
                                              int* __restrict__ rowptr, int N,
                                              int E, int CAP) {
  __shared__ int s[256];
  const int t = threadIdx.x;
  const int c = gcur[t] - t * CAP;
  s[t] = c;
  __syncthreads();
#pragma unroll
  for (int off = 1; off < 256; off <<= 1) {
    const int add = (t >= off) ? s[t - off] : 0;
    __syncthreads();
    s[t] += add;
    __syncthreads();
  }
  cbase[t] = s[t] - c;
  if (t == 0) rowptr[N] = E;
}

// ---- fine placement, 4 sub-blocks per bucket, (dst,rel)-sorted output ----
__global__ __launch_bounds__(256) void f3_fine4(
    const unsigned* __restrict__ staging, const int* __restrict__ gcur,
    const int* __restrict__ cbase, int* __restrict__ rowptr,
    int* __restrict__ srcet, int N, int CAP) {
  __shared__ int hist[256];
  __shared__ int sc[256];
  __shared__ int lcur[256];
  __shared__ int before;
  const int cb = blockIdx.x >> 2;
  const int sub = blockIdx.x & 3;
  const int t = threadIdx.x;
  const int s0 = cb * CAP;
  const int s1 = gcur[cb];  // s0 + count
  const int dlo = sub << 6;

  hist[t] = 0;
  if (t == 0) before = 0;
  __syncthreads();

  int myb = 0;
  for (int i = s0 + t; i < s1; i += 256) {
    const unsigned r = staging[i];
    const int dl = (int)(r >> 24);
    const int off = dl - dlo;
    if ((unsigned)off < 64u)
      atomicAdd(&hist[(off << 2) | (int)(r & 3u)], 1);
    else if (dl < dlo)
      ++myb;
  }
#pragma unroll
  for (int off = 32; off > 0; off >>= 1) myb += __shfl_down(myb, off);
  if ((t & 63) == 0 && myb) atomicAdd(&before, myb);
  __syncthreads();

  const int v = hist[t];
  sc[t] = v;
  __syncthreads();
#pragma unroll
  for (int off = 1; off < 256; off <<= 1) {
    const int add = (t >= off) ? sc[t - off] : 0;
    __syncthreads();
    sc[t] += add;
    __syncthreads();
  }
  const int base = cbase[cb] + before + sc[t] - v;
  lcur[t] = base;
  if ((t & 3) == 0) {
    const int dn = (cb << 8) + dlo + (t >> 2);
    if (dn < N) rowptr[dn] = base;
  }
  __syncthreads();

  for (int i = s0 + t; i < s1; i += 256) {
    const unsigned r = staging[i];
    const int dl = (int)(r >> 24);
    const int off = dl - dlo;
    if ((unsigned)off < 64u) {
      const int pos = atomicAdd(&lcur[(off << 2) | (int)(r & 3u)], 1);
      srcet[pos] = (int)(r & 0xFFFFFFu);
    }
  }
}

// ========== per-node relation gather (f32 reads, bf16 aggr writes) ==========
#define ACCUM(se, v)                                                         \
  {                                                                          \
    const int r_ = (se) & 3;                                                 \
    if (r_ == 0) { a0.x += v.x; a0.y += v.y; a0.z += v.z; a0.w += v.w; }     \
    else if (r_ == 1) { a1.x += v.x; a1.y += v.y; a1.z += v.z; a1.w += v.w; }\
    else if (r_ == 2) { a2.x += v.x; a2.y += v.y; a2.z += v.z; a2.w += v.w; }\
    else { a3.x += v.x; a3.y += v.y; a3.z += v.z; a3.w += v.w; }             \
  }

__global__ __launch_bounds__(256) void gather_rel(
    const float* __restrict__ h, const int* __restrict__ rowptr,
    const int* __restrict__ srcet, ushort* __restrict__ aggr_bf, int N) {
  const int n = blockIdx.x * 4 + (threadIdx.x >> 6);
  const int lane = threadIdx.x & 63;
  const int g = lane >> 4;    // relation group 0..3 / edge slot
  const int t = lane & 15;    // float4 chunk 0..15
  if (n >= N) return;
  const int beg = rowptr[n], end = rowptr[n + 1];

  float4 a0 = make_float4(0.f, 0.f, 0.f, 0.f);
  float4 a1 = a0, a2 = a0, a3 = a0;

  int j = beg + g;
  for (; j + 12 < end; j += 16) {
    const int se0 = srcet[j];
    const int se1 = srcet[j + 4];
    const int se2 = srcet[j + 8];
    const int se3 = srcet[j + 12];
    float4 v0 = *(const float4*)(h + ((size_t)(se0 >> 2) << 6) + (t << 2));
    float4 v1 = *(const float4*)(h + ((size_t)(se1 >> 2) << 6) + (t << 2));
    float4 v2 = *(const float4*)(h + ((size_t)(se2 >> 2) << 6) + (t << 2));
    float4 v3 = *(const float4*)(h + ((size_t)(se3 >> 2) << 6) + (t << 2));
    ACCUM(se0, v0);
    ACCUM(se1, v1);
    ACCUM(se2, v2);
    ACCUM(se3, v3);
  }
  for (; j < end; j += 4) {
    const int se0 = srcet[j];
    float4 v0 = *(const float4*)(h + ((size_t)(se0 >> 2) << 6) + (t << 2));
    ACCUM(se0, v0);
  }

#pragma unroll
  for (int off = 16; off <= 32; off <<= 1) {
    a0.x += __shfl_xor(a0.x, off); a0.y += __shfl_xor(a0.y, off);
    a0.z += __shfl_xor(a0.z, off); a0.w += __shfl_xor(a0.w, off);
    a1.x += __shfl_xor(a1.x, off); a1.y += __shfl_xor(a1.y, off);
    a1.z += __shfl_xor(a1.z, off); a1.w += __shfl_xor(a1.w, off);
    a2.x += __shfl_xor(a2.x, off); a2.y += __shfl_xor(a2.y, off);
    a2.z += __shfl_xor(a2.z, off); a2.w += __shfl_xor(a2.w, off);
    a3.x += __shfl_xor(a3.x, off); a3.y += __shfl_xor(a3.y, off);
    a3.z += __shfl_xor(a3.z, off); a3.w += __shfl_xor(a3.w, off);
  }

  const float4 res = (g == 0) ? a0 : (g == 1) ? a1 : (g == 2) ? a2 : a3;
  uint2 p;
  p.x = f2bf(res.x) | (f2bf(res.y) << 16);
  p.y = f2bf(res.z) | (f2bf(res.w) << 16);
  *(uint2*)(aggr_bf + ((size_t)n << 8) + (g << 6) + (t << 2)) = p;
}

// ===== dense (LDS-tiled, bf16 aggr): hnext = relu(sum_r aggr@Wrel + hin@Wloop + brel) =====
__global__ __launch_bounds__(256) void rgcn_dense_t(
    const ushort* __restrict__ aggr_bf, const float* __restrict__ hin,
    const float* __restrict__ Wrel, const float* __restrict__ Wloop,
    const float* __restrict__ brel, float* __restrict__ hnext, int N) {
  __shared__ float tile[64 * 65];
  const int tid = threadIdx.x;
  const int lane = tid & 63;
  const int wv = tid >> 6;
  const int c0 = __builtin_amdgcn_readfirstlane(wv << 4);
  const int n0 = blockIdx.x * 64;

  float acc[16];
#pragma unroll
  for (int jj = 0; jj < 16; ++jj) acc[jj] = brel[c0 + jj];

#pragma unroll 1
  for (int m = 0; m < 5; ++m) {
    __syncthreads();
    if (m < 4) {
#pragma unroll
      for (int q = 0; q < 2; ++q) {
        const int f = q * 256 + tid;  // 0..511
        const int row = f >> 3;       // 0..63
        const int c8 = (f & 7) << 3;  // 0..56
        const int nn = n0 + row;
        float v[8] = {0.f, 0.f, 0.f, 0.f, 0.f, 0.f, 0.f, 0.f};
        if (nn < N) {
          const uint4 raw =
              *(const uint4*)(aggr_bf + ((size_t)nn << 8) + (m << 6) + c8);
          unpack8(raw, v);
        }
        float* d = tile + row * 65 + c8;
#pragma unroll
        for (int k = 0; k < 8; ++k) d[k] = v[k];
      }
    } else {
#pragma unroll
      for (int q = 0; q < 4; ++q) {
        const int f = q * 256 + tid;
        const int row = f >> 4;
        const int c4 = (f & 15) << 2;
        const int nn = n0 + row;
        float4 v = make_float4(0.f, 0.f, 0.f, 0.f);
        if (nn < N) v = *(const float4*)(hin + ((size_t)nn << 6) + c4);
        float* d = tile + row * 65 + c4;
        d[0] = v.x; d[1] = v.y; d[2] = v.z; d[3] = v.w;
      }
    }
    __syncthreads();
    const float* __restrict__ W =
        (m < 4) ? (Wrel + (size_t)m * DD * DD) : Wloop;
    const float* trow = tile + lane * 65;
#pragma unroll
    for (int k = 0; k < DD; ++k) {
      const float hk = trow[k];
#pragma unroll
      for (int jj = 0; jj < 16; ++jj)
        acc[jj] = fmaf(hk, W[k * DD + c0 + jj], acc[jj]);
    }
  }

  __syncthreads();
  {
    float* d = tile + lane * 65 + c0;
#pragma unroll
    for (int jj = 0; jj < 16; ++jj) d[jj] = fmaxf(acc[jj], 0.f);
  }
  __syncthreads();
#pragma unroll
  for (int q = 0; q < 4; ++q) {
    const int f = q * 256 + tid;
    const int row = f >> 4;
    const int c4 = (f & 15) << 2;
    const int nn = n0 + row;
    if (nn < N) {
      const float* s = tile + row * 65 + c4;
      *(float4*)(hnext + ((size_t)nn << 6) + c4) =
          make_float4(s[0], s[1], s[2], s[3]);
    }
  }
}

// ===== GAT projection (LDS-tiled): z = h@Wg (h already relu'd), el/er + gmax =====
__global__ __launch_bounds__(256) void gemm_gat_t(
    const float* __restrict__ hin, const float* __restrict__ Wg,
    const float* __restrict__ al, const float* __restrict__ ar,
    float* __restrict__ z, float* __restrict__ el, float* __restrict__ er,
    unsigned* __restrict__ genc, int N) {
  __shared__ float tile[64 * 65];
  __shared__ float sel[4][64];
  __shared__ float ser[4][64];
  const int tid = threadIdx.x;
  const int lane = tid & 63;
  const int wv = tid >> 6;
  const int c0 = __builtin_amdgcn_readfirstlane(wv << 4);
  const int n0 = blockIdx.x * 64;
  const int n = n0 + lane;

#pragma unroll
  for (int q = 0; q < 4; ++q) {
    const int f = q * 256 + tid;
    const int row = f >> 4;
    const int c4 = (f & 15) << 2;
    const int nn = n0 + row;
    float4 v = make_float4(0.f, 0.f, 0.f, 0.f);
    if (nn < N) v = *(const float4*)(hin + ((size_t)nn << 6) + c4);
    float* d = tile + row * 65 + c4;
    d[0] = v.x; d[1] = v.y; d[2] = v.z; d[3] = v.w;
  }
  __syncthreads();

  float acc[16];
#pragma unroll
  for (int jj = 0; jj < 16; ++jj) acc[jj] = 0.f;
  {
    const float* trow = tile + lane * 65;
#pragma unroll
    for (int k = 0; k < DD; ++k) {
      const float hk = trow[k];
#pragma unroll
      for (int jj = 0; jj < 16; ++jj)
        acc[jj] = fmaf(hk, Wg[k * DD + c0 + jj], acc[jj]);
    }
  }

  float pl = 0.f, pr = 0.f;
#pragma unroll
  for (int jj = 0; jj < 16; ++jj) {
    pl = fmaf(acc[jj], al[c0 + jj], pl);
    pr = fmaf(acc[jj], ar[c0 + jj], pr);
  }
  sel[wv][lane] = pl;
  ser[wv][lane] = pr;

  __syncthreads();
  {
    float* d = tile + lane * 65 + c0;
#pragma unroll
    for (int jj = 0; jj < 16; ++jj) d[jj] = acc[jj];
  }
  __syncthreads();
#pragma unroll
  for (int q = 0; q < 4; ++q) {
    const int f = q * 256 + tid;
    const int row = f >> 4;
    const int c4 = (f & 15) << 2;
    const int nn = n0 + row;
    if (nn < N) {
      const float* s = tile + row * 65 + c4;
      *(float4*)(z + ((size_t)nn << 6) + c4) =
          make_float4(s[0], s[1], s[2], s[3]);
    }
  }
  if (wv == 0) {
    float eln = sel[0][lane] + sel[1][lane] + sel[2][lane] + sel[3][lane];
    float ern = ser[0][lane] + ser[1][lane] + ser[2][lane] + ser[3][lane];
    if (n < N) {
      el[n] = eln;
      er[n] = ern;
    }
    float mx = (n < N) ? eln : -1e30f;
#pragma unroll
    for (int off = 32; off > 0; off >>= 1) mx = fmaxf(mx, __shfl_xor(mx, off));
    if (lane == 0) atomicMax(genc, enc_f32(mx));
  }
}

// ========= fused GAT aggregation, single pass (upper-bound max) =========
__global__ __launch_bounds__(256) void gat_fused(
    const float* __restrict__ z, const float* __restrict__ el,
    const float* __restrict__ er, const int* __restrict__ rowptr,
    const int* __restrict__ srcet, const unsigned* __restrict__ genc,
    float* __restrict__ hg, int N) {
  const int n = blockIdx.x * 4 + (threadIdx.x >> 6);
  const int lane = threadIdx.x & 63;
  const int g = lane >> 4;
  const int t = lane & 15;
  if (n >= N) return;
  const int beg = rowptr[n], end = rowptr[n + 1];
  const float ern = er[n];
  float mb = dec_f32(*genc) + ern;
  mb = (mb > 0.f) ? mb : 0.2f * mb;

  float4 num = make_float4(0.f, 0.f, 0.f, 0.f);
  float den = 0.f;
  for (int j = beg + g; j < end; j += 4) {
    const int se = srcet[j];
    const int s = se >> 2;
    float x = el[s] + ern;
    x = (x > 0.f) ? x : 0.2f * x;
    const float w = __expf(x - mb);
    den += w;
    float4 v = *(const float4*)(z + ((size_t)s << 6) + (t << 2));
    num.x = fmaf(w, v.x, num.x);
    num.y = fmaf(w, v.y, num.y);
    num.z = fmaf(w, v.z, num.z);
    num.w = fmaf(w, v.w, num.w);
  }
#pragma unroll
  for (int off = 16; off <= 32; off <<= 1) {
    num.x += __shfl_xor(num.x, off);
    num.y += __shfl_xor(num.y, off);
    num.z += __shfl_xor(num.z, off);
    num.w += __shfl_xor(num.w, off);
    den += __shfl_xor(den, off);
  }
  if (g == 0) {
    const float inv = 1.f / fmaxf(den, 1e-9f);
    float4 o = make_float4(num.x * inv, num.y * inv, num.z * inv, num.w * inv);
    *(float4*)(hg + ((size_t)n << 6) + (t << 2)) = o;
  }
}

// ================= pooled head, two-level =================
__global__ __launch_bounds__(256) void pool_head2(
    const float* __restrict__ hg, const float* __restrict__ Wd,
    const int* __restrict__ gids, float* __restrict__ out, int N, int B) {
  __shared__ float acc[1024];
  for (int i = threadIdx.x; i < B; i += 256) acc[i] = 0.f;
  __syncthreads();

  const int wv = threadIdx.x >> 6;
  const int lane = threadIdx.x & 63;
  const int sub = lane & 3;
  const int idx = lane >> 2;

  const float4 w0 = *(const float4*)(Wd + (sub << 4) + 0);
  const float4 w1 = *(const float4*)(Wd + (sub << 4) + 4);
  const float4 w2 = *(const float4*)(Wd + (sub << 4) + 8);
  const float4 w3 = *(const float4*)(Wd + (sub << 4) + 12);

  const int base0 = blockIdx.x * POOL_NPB;
#pragma unroll 1
  for (int it = 0; it < POOL_NPB / 64; ++it) {
    const int n = base0 + it * 64 + wv * 16 + idx;
    if (n < N) {
      const float* p = hg + ((size_t)n << 6) + (sub << 4);
      const float4 v0 = *(const float4*)(p + 0);
      const float4 v1 = *(const float4*)(p + 4);
      const float4 v2 = *(const float4*)(p + 8);
      const float4 v3 = *(const float4*)(p + 12);
      float s = v0.x * w0.x + v0.y * w0.y + v0.z * w0.z + v0.w * w0.w;
      s = fmaf(v1.x, w1.x, s); s = fmaf(v1.y, w1.y, s);
      s = fmaf(v1.z, w1.z, s); s = fmaf(v1.w, w1.w, s);
      s = fmaf(v2.x, w2.x, s); s = fmaf(v2.y, w2.y, s);
      s = fmaf(v2.z, w2.z, s); s = fmaf(v2.w, w2.w, s);
      s = fmaf(v3.x, w3.x, s); s = fmaf(v3.y, w3.y, s);
      s = fmaf(v3.z, w3.z, s); s = fmaf(v3.w, w3.w, s);
      s += __shfl_xor(s, 1);
      s += __shfl_xor(s, 2);
      if (sub == 0) atomicAdd(&acc[gids[n]], s);
    }
  }
  __syncthreads();
  for (int i = threadIdx.x; i < B; i += 256) {
    const float v = acc[i];
    if (v != 0.f) unsafeAtomicAdd(out + i, v);
  }
}

__global__ void init_out_k(float* out, const float* bd, int n, unsigned* genc,
                           int* gcur, int CAP) {
  int i = blockIdx.x * blockDim.x + threadIdx.x;
  if (i < n) out[i] = bd[0];
  if (i < 256) gcur[i] = i * CAP;
  if (i == 0) *genc = enc_f32(-1e30f);
}

// ================= launch =================
extern "C" void kernel_launch(void* const* d_in, const int* in_sizes, int n_in,
                              void* d_out, int out_size, void* d_ws,
                              size_t ws_size, hipStream_t stream) {
  const float* h0 = (const float*)d_in[0];
  const float* Wrel = (const float*)d_in[1];
  const float* Wloop = (const float*)d_in[2];
  const float* brel = (const float*)d_in[3];
  const float* Wg = (const float*)d_in[4];
  const float* al = (const float*)d_in[5];
  const float* ar = (const float*)d_in[6];
  const float* Wd = (const float*)d_in[7];
  const float* bd = (const float*)d_in[8];
  const int* src = (const int*)d_in[9];
  const int* dst = (const int*)d_in[10];
  const int* et = (const int*)d_in[11];
  const int* gids = (const int*)d_in[12];

  const int N = in_sizes[0] / DD;
  const int E = in_sizes[9];
  const int L = in_sizes[2] / (DD * DD);
  float* out = (float*)d_out;
  const int CAP = (E / 256) * 2;  // fixed bucket capacity (2x mean)

  // ---- workspace layout ----
  float* wsf = (float*)d_ws;
  float* hA = wsf;                              // N*64 f32
  float* hB = hA + (size_t)N * DD;              // N*64 f32
  ushort* aggr_bf = (ushort*)(hB + (size_t)N * DD);  // N*256 bf16 (25.6MB region)
  int* rowptr = (int*)(aggr_bf + (size_t)N * 256);   // N+1
  int* srcet = rowptr + N + 1;                  // E
  float* el = (float*)(srcet + E);              // N
  float* er = el + N;                           // N
  int* gcur = (int*)(er + N);                   // 256
  int* cbase = gcur + 256;                      // 256
  unsigned* genc = (unsigned*)(cbase + 256);    // 1
  unsigned* staging = (unsigned*)aggr_bf;       // 256*CAP uints, overlays aggr
  float* hg = (float*)aggr_bf;                  // overlay after last dense

  dim3 b256(256);
  const int grid_dense = (N + 63) / 64;
  const int grid_n4 = (N + 3) / 4;
  const int nfb = (E + EPB - 1) / EPB;
  const int ncb = (N + 255) >> 8;

  hipLaunchKernelGGL(init_out_k, dim3((max(out_size, 256) + 255) / 256), b256,
                     0, stream, out, bd, out_size, genc, gcur, CAP);

  // ---- CSR build (fixed-capacity buckets, (dst,rel)-sorted output) ----
  hipLaunchKernelGGL(f2_coarse, dim3(nfb), b256, 0, stream, src, dst, et, gcur,
                     staging, E);
  hipLaunchKernelGGL(cscan2, dim3(1), b256, 0, stream, gcur, cbase, rowptr, N,
                     E, CAP);
  hipLaunchKernelGGL(f3_fine4, dim3(ncb * 4), b256, 0, stream, staging, gcur,
                     cbase, rowptr, srcet, N, CAP);

  // ---- RGCN layers (dense stores post-relu h; aggr in bf16) ----
  const float* cur = h0;
  float* nxt = hA;
  for (int l = 0; l < L; ++l) {
    hipLaunchKernelGGL(gather_rel, dim3(grid_n4), b256, 0, stream, cur, rowptr,
                       srcet, aggr_bf, N);
    hipLaunchKernelGGL(rgcn_dense_t, dim3(grid_dense), b256, 0, stream, aggr_bf,
                       cur, Wrel + (size_t)l * 4 * DD * DD,
                       Wloop + (size_t)l * DD * DD, brel + (size_t)l * DD, nxt,
                       N);
    cur = nxt;
    nxt = (cur == hA) ? hB : hA;
  }

  // ---- GAT ----
  float* zb = nxt;
  hipLaunchKernelGGL(gemm_gat_t, dim3(grid_dense), b256, 0, stream, cur, Wg, al,
                     ar, zb, el, er, genc, N);
  hipLaunchKernelGGL(gat_fused, dim3(grid_n4), b256, 0, stream, zb, el, er,
                     rowptr, srcet, genc, hg, N);

  const int grid_pool = (N + POOL_NPB - 1) / POOL_NPB;
  hipLaunchKernelGGL(pool_head2, dim3(grid_pool), b256, 0, stream, hg, Wd, gids,
                     out, N, out_size);
}

// Round 15
// 529.642 us; speedup vs baseline: 1.6569x; 1.1062x over previous
//
#include <hip/hip_runtime.h>

#define DD 64
#define POOL_NPB 512
#define EPB 1024  // edges per block in fill pipeline

__device__ __forceinline__ unsigned enc_f32(float x) {
  unsigned u = __float_as_uint(x);
  return (u & 0x80000000u) ? ~u : (u | 0x80000000u);
}
__device__ __forceinline__ float dec_f32(unsigned k) {
  return (k & 0x80000000u) ? __uint_as_float(k ^ 0x80000000u)
                           : __uint_as_float(~k);
}
__device__ __forceinline__ unsigned f2bf(float x) {
  unsigned u = __float_as_uint(x);
  return (u + 0x7fffu + ((u >> 16) & 1u)) >> 16;
}
__device__ __forceinline__ void unpack8(const uint4 raw, float* v) {
  v[0] = __uint_as_float(raw.x << 16);
  v[1] = __uint_as_float(raw.x & 0xffff0000u);
  v[2] = __uint_as_float(raw.y << 16);
  v[3] = __uint_as_float(raw.y & 0xffff0000u);
  v[4] = __uint_as_float(raw.z << 16);
  v[5] = __uint_as_float(raw.z & 0xffff0000u);
  v[6] = __uint_as_float(raw.w << 16);
  v[7] = __uint_as_float(raw.w & 0xffff0000u);
}
__device__ __forceinline__ float4 unpack4(const uint2 r) {
  return make_float4(__uint_as_float(r.x << 16),
                     __uint_as_float(r.x & 0xffff0000u),
                     __uint_as_float(r.y << 16),
                     __uint_as_float(r.y & 0xffff0000u));
}

// ================= f32 -> bf16 conversion (h0) =================
__global__ __launch_bounds__(256) void conv_bf16(const float* __restrict__ x,
                                                 ushort* __restrict__ xb,
                                                 int n4) {
  int i = blockIdx.x * 256 + threadIdx.x;
  if (i < n4) {
    float4 v = ((const float4*)x)[i];
    uint2 o;
    o.x = f2bf(v.x) | (f2bf(v.y) << 16);
    o.y = f2bf(v.z) | (f2bf(v.w) << 16);
    ((uint2*)xb)[i] = o;
  }
}

// ---- coarse scatter: LDS-reordered, fixed-capacity bucket runs (4B records) ----
__global__ __launch_bounds__(256) void f2_coarse(
    const int* __restrict__ src, const int* __restrict__ dst,
    const int* __restrict__ et, int* __restrict__ gcur,
    unsigned* __restrict__ staging, int E) {
  __shared__ int lcnt[256];
  __shared__ int sc[256];
  __shared__ int lbase[256];
  __shared__ int gb[256];
  __shared__ unsigned rec[EPB];
  __shared__ unsigned char rbk[EPB];

  const int t = threadIdx.x;
  const int base = blockIdx.x * EPB;
  const int bc = min(EPB, E - base);

  lcnt[t] = 0;
  __syncthreads();

  int d_[EPB / 256], se_[EPB / 256], rk_[EPB / 256];
#pragma unroll
  for (int k = 0; k < EPB / 256; ++k) {
    const int e = base + k * 256 + t;
    if (e < E) {
      const int d = dst[e];
      d_[k] = d;
      se_[k] = (src[e] << 2) | et[e];
      rk_[k] = atomicAdd(&lcnt[d >> 8], 1);
    } else {
      d_[k] = -1;
    }
  }
  __syncthreads();

  const int lv = lcnt[t];
  sc[t] = lv;
  __syncthreads();
#pragma unroll
  for (int off = 1; off < 256; off <<= 1) {
    const int add = (t >= off) ? sc[t - off] : 0;
    __syncthreads();
    sc[t] += add;
    __syncthreads();
  }
  lbase[t] = sc[t] - lv;
  gb[t] = lv ? atomicAdd(&gcur[t], lv) : 0;
  __syncthreads();

#pragma unroll
  for (int k = 0; k < EPB / 256; ++k) {
    if (d_[k] >= 0) {
      const int cb = d_[k] >> 8;
      const int pos = lbase[cb] + rk_[k];
      rec[pos] = ((unsigned)(d_[k] & 255) << 24) | (unsigned)se_[k];
      rbk[pos] = (unsigned char)cb;
    }
  }
  __syncthreads();

  for (int idx = t; idx < bc; idx += 256) {
    const int cb = rbk[idx];
    staging[gb[cb] + (idx - lbase[cb])] = rec[idx];
  }
}

// ---- scan bucket counts (from gcur) -> cbase; set rowptr[N] ----
__global__ __launch_bounds__(256) void cscan2(const int* __restrict__ gcur,
                                              int* __restrict__ cbase,
                                              int* __restrict__ rowptr, int N,
                                              int E, int CAP) {
  __shared__ int s[256];
  const int t = threadIdx.x;
  const int c = gcur[t] - t * CAP;
  s[t] = c;
  __syncthreads();
#pragma unroll
  for (int off = 1; off < 256; off <<= 1) {
    const int add = (t >= off) ? s[t - off] : 0;
    __syncthreads();
    s[t] += add;
    __syncthreads();
  }
  cbase[t] = s[t] - c;
  if (t == 0) rowptr[N] = E;
}

// ---- fine placement, 4 sub-blocks per bucket, (dst,rel)-sorted output ----
__global__ __launch_bounds__(256) void f3_fine4(
    const unsigned* __restrict__ staging, const int* __restrict__ gcur,
    const int* __restrict__ cbase, int* __restrict__ rowptr,
    int* __restrict__ srcet, int N, int CAP) {
  __shared__ int hist[256];
  __shared__ int sc[256];
  __shared__ int lcur[256];
  __shared__ int before;
  const int cb = blockIdx.x >> 2;
  const int sub = blockIdx.x & 3;
  const int t = threadIdx.x;
  const int s0 = cb * CAP;
  const int s1 = gcur[cb];
  const int dlo = sub << 6;

  hist[t] = 0;
  if (t == 0) before = 0;
  __syncthreads();

  int myb = 0;
  for (int i = s0 + t; i < s1; i += 256) {
    const unsigned r = staging[i];
    const int dl = (int)(r >> 24);
    const int off = dl - dlo;
    if ((unsigned)off < 64u)
      atomicAdd(&hist[(off << 2) | (int)(r & 3u)], 1);
    else if (dl < dlo)
      ++myb;
  }
#pragma unroll
  for (int off = 32; off > 0; off >>= 1) myb += __shfl_down(myb, off);
  if ((t & 63) == 0 && myb) atomicAdd(&before, myb);
  __syncthreads();

  const int v = hist[t];
  sc[t] = v;
  __syncthreads();
#pragma unroll
  for (int off = 1; off < 256; off <<= 1) {
    const int add = (t >= off) ? sc[t - off] : 0;
    __syncthreads();
    sc[t] += add;
    __syncthreads();
  }
  const int base = cbase[cb] + before + sc[t] - v;
  lcur[t] = base;
  if ((t & 3) == 0) {
    const int dn = (cb << 8) + dlo + (t >> 2);
    if (dn < N) rowptr[dn] = base;
  }
  __syncthreads();

  for (int i = s0 + t; i < s1; i += 256) {
    const unsigned r = staging[i];
    const int dl = (int)(r >> 24);
    const int off = dl - dlo;
    if ((unsigned)off < 64u) {
      const int pos = atomicAdd(&lcur[(off << 2) | (int)(r & 3u)], 1);
      srcet[pos] = (int)(r & 0xFFFFFFu);
    }
  }
}

// ====== per-node relation gather (bf16 rows, 16 lanes/edge, 4 in flight) ======
#define ACCUM(se, v)                                                         \
  {                                                                          \
    const int r_ = (se) & 3;                                                 \
    if (r_ == 0) { a0.x += v.x; a0.y += v.y; a0.z += v.z; a0.w += v.w; }     \
    else if (r_ == 1) { a1.x += v.x; a1.y += v.y; a1.z += v.z; a1.w += v.w; }\
    else if (r_ == 2) { a2.x += v.x; a2.y += v.y; a2.z += v.z; a2.w += v.w; }\
    else { a3.x += v.x; a3.y += v.y; a3.z += v.z; a3.w += v.w; }             \
  }

__global__ __launch_bounds__(256) void gather_rel(
    const ushort* __restrict__ hb, const int* __restrict__ rowptr,
    const int* __restrict__ srcet, ushort* __restrict__ aggr_bf, int N) {
  const int n = blockIdx.x * 4 + (threadIdx.x >> 6);
  const int lane = threadIdx.x & 63;
  const int g = lane >> 4;    // edge slot 0..3
  const int t = lane & 15;    // elements [4t, 4t+4)
  if (n >= N) return;
  const int beg = rowptr[n], end = rowptr[n + 1];

  float4 a0 = make_float4(0.f, 0.f, 0.f, 0.f);
  float4 a1 = a0, a2 = a0, a3 = a0;

  int j = beg + g;
  for (; j + 12 < end; j += 16) {
    const int se0 = srcet[j];
    const int se1 = srcet[j + 4];
    const int se2 = srcet[j + 8];
    const int se3 = srcet[j + 12];
    const uint2 r0 = *(const uint2*)(hb + ((size_t)(se0 >> 2) << 6) + (t << 2));
    const uint2 r1 = *(const uint2*)(hb + ((size_t)(se1 >> 2) << 6) + (t << 2));
    const uint2 r2 = *(const uint2*)(hb + ((size_t)(se2 >> 2) << 6) + (t << 2));
    const uint2 r3 = *(const uint2*)(hb + ((size_t)(se3 >> 2) << 6) + (t << 2));
    const float4 v0 = unpack4(r0);
    const float4 v1 = unpack4(r1);
    const float4 v2 = unpack4(r2);
    const float4 v3 = unpack4(r3);
    ACCUM(se0, v0);
    ACCUM(se1, v1);
    ACCUM(se2, v2);
    ACCUM(se3, v3);
  }
  for (; j < end; j += 4) {
    const int se0 = srcet[j];
    const uint2 r0 = *(const uint2*)(hb + ((size_t)(se0 >> 2) << 6) + (t << 2));
    const float4 v0 = unpack4(r0);
    ACCUM(se0, v0);
  }

#pragma unroll
  for (int off = 16; off <= 32; off <<= 1) {
    a0.x += __shfl_xor(a0.x, off); a0.y += __shfl_xor(a0.y, off);
    a0.z += __shfl_xor(a0.z, off); a0.w += __shfl_xor(a0.w, off);
    a1.x += __shfl_xor(a1.x, off); a1.y += __shfl_xor(a1.y, off);
    a1.z += __shfl_xor(a1.z, off); a1.w += __shfl_xor(a1.w, off);
    a2.x += __shfl_xor(a2.x, off); a2.y += __shfl_xor(a2.y, off);
    a2.z += __shfl_xor(a2.z, off); a2.w += __shfl_xor(a2.w, off);
    a3.x += __shfl_xor(a3.x, off); a3.y += __shfl_xor(a3.y, off);
    a3.z += __shfl_xor(a3.z, off); a3.w += __shfl_xor(a3.w, off);
  }

  const float4 res = (g == 0) ? a0 : (g == 1) ? a1 : (g == 2) ? a2 : a3;
  uint2 p;
  p.x = f2bf(res.x) | (f2bf(res.y) << 16);
  p.y = f2bf(res.z) | (f2bf(res.w) << 16);
  *(uint2*)(aggr_bf + ((size_t)n << 8) + (g << 6) + (t << 2)) = p;
}

// == dense (LDS-tiled, bf16 in/out): hb_out = bf16(relu(sum_r aggr@Wrel + h@Wloop + b)) ==
__global__ __launch_bounds__(256) void rgcn_dense_t(
    const ushort* __restrict__ aggr_bf, const ushort* __restrict__ hb_in,
    const float* __restrict__ Wrel, const float* __restrict__ Wloop,
    const float* __restrict__ brel, ushort* __restrict__ hb_out, int N) {
  __shared__ float tile[64 * 65];
  const int tid = threadIdx.x;
  const int lane = tid & 63;
  const int wv = tid >> 6;
  const int c0 = __builtin_amdgcn_readfirstlane(wv << 4);
  const int n0 = blockIdx.x * 64;

  float acc[16];
#pragma unroll
  for (int jj = 0; jj < 16; ++jj) acc[jj] = brel[c0 + jj];

#pragma unroll 1
  for (int m = 0; m < 5; ++m) {
    __syncthreads();
#pragma unroll
    for (int q = 0; q < 2; ++q) {
      const int f = q * 256 + tid;  // 0..511
      const int row = f >> 3;       // 0..63
      const int c8 = (f & 7) << 3;  // 0..56
      const int nn = n0 + row;
      float v[8] = {0.f, 0.f, 0.f, 0.f, 0.f, 0.f, 0.f, 0.f};
      if (nn < N) {
        const ushort* s = (m < 4) ? (aggr_bf + ((size_t)nn << 8) + (m << 6) + c8)
                                  : (hb_in + ((size_t)nn << 6) + c8);
        const uint4 raw = *(const uint4*)s;
        unpack8(raw, v);
      }
      float* d = tile + row * 65 + c8;
#pragma unroll
      for (int k = 0; k < 8; ++k) d[k] = v[k];
    }
    __syncthreads();
    const float* __restrict__ W =
        (m < 4) ? (Wrel + (size_t)m * DD * DD) : Wloop;
    const float* trow = tile + lane * 65;
#pragma unroll
    for (int k = 0; k < DD; ++k) {
      const float hk = trow[k];
#pragma unroll
      for (int jj = 0; jj < 16; ++jj)
        acc[jj] = fmaf(hk, W[k * DD + c0 + jj], acc[jj]);
    }
  }

  __syncthreads();
  {
    float* d = tile + lane * 65 + c0;
#pragma unroll
    for (int jj = 0; jj < 16; ++jj) d[jj] = fmaxf(acc[jj], 0.f);
  }
  __syncthreads();
#pragma unroll
  for (int q = 0; q < 2; ++q) {
    const int f = q * 256 + tid;
    const int row = f >> 3;
    const int c8 = (f & 7) << 3;
    const int nn = n0 + row;
    if (nn < N) {
      const float* s = tile + row * 65 + c8;
      uint4 p;
      p.x = f2bf(s[0]) | (f2bf(s[1]) << 16);
      p.y = f2bf(s[2]) | (f2bf(s[3]) << 16);
      p.z = f2bf(s[4]) | (f2bf(s[5]) << 16);
      p.w = f2bf(s[6]) | (f2bf(s[7]) << 16);
      *(uint4*)(hb_out + ((size_t)nn << 6) + c8) = p;
    }
  }
}

// ===== GAT projection (LDS-tiled, bf16 in/out): z = h@Wg, el/er + gmax =====
__global__ __launch_bounds__(256) void gemm_gat_t(
    const ushort* __restrict__ hb_in, const float* __restrict__ Wg,
    const float* __restrict__ al, const float* __restrict__ ar,
    ushort* __restrict__ zb, float* __restrict__ el, float* __restrict__ er,
    unsigned* __restrict__ genc, int N) {
  __shared__ float tile[64 * 65];
  __shared__ float sel[4][64];
  __shared__ float ser[4][64];
  const int tid = threadIdx.x;
  const int lane = tid & 63;
  const int wv = tid >> 6;
  const int c0 = __builtin_amdgcn_readfirstlane(wv << 4);
  const int n0 = blockIdx.x * 64;
  const int n = n0 + lane;

#pragma unroll
  for (int q = 0; q < 2; ++q) {
    const int f = q * 256 + tid;
    const int row = f >> 3;
    const int c8 = (f & 7) << 3;
    const int nn = n0 + row;
    float v[8] = {0.f, 0.f, 0.f, 0.f, 0.f, 0.f, 0.f, 0.f};
    if (nn < N) {
      const uint4 raw = *(const uint4*)(hb_in + ((size_t)nn << 6) + c8);
      unpack8(raw, v);
    }
    float* d = tile + row * 65 + c8;
#pragma unroll
    for (int k = 0; k < 8; ++k) d[k] = v[k];
  }
  __syncthreads();

  float acc[16];
#pragma unroll
  for (int jj = 0; jj < 16; ++jj) acc[jj] = 0.f;
  {
    const float* trow = tile + lane * 65;
#pragma unroll
    for (int k = 0; k < DD; ++k) {
      const float hk = trow[k];
#pragma unroll
      for (int jj = 0; jj < 16; ++jj)
        acc[jj] = fmaf(hk, Wg[k * DD + c0 + jj], acc[jj]);
    }
  }

  float pl = 0.f, pr = 0.f;
#pragma unroll
  for (int jj = 0; jj < 16; ++jj) {
    pl = fmaf(acc[jj], al[c0 + jj], pl);
    pr = fmaf(acc[jj], ar[c0 + jj], pr);
  }
  sel[wv][lane] = pl;
  ser[wv][lane] = pr;

  __syncthreads();
  {
    float* d = tile + lane * 65 + c0;
#pragma unroll
    for (int jj = 0; jj < 16; ++jj) d[jj] = acc[jj];
  }
  __syncthreads();
#pragma unroll
  for (int q = 0; q < 2; ++q) {
    const int f = q * 256 + tid;
    const int row = f >> 3;
    const int c8 = (f & 7) << 3;
    const int nn = n0 + row;
    if (nn < N) {
      const float* s = tile + row * 65 + c8;
      uint4 p;
      p.x = f2bf(s[0]) | (f2bf(s[1]) << 16);
      p.y = f2bf(s[2]) | (f2bf(s[3]) << 16);
      p.z = f2bf(s[4]) | (f2bf(s[5]) << 16);
      p.w = f2bf(s[6]) | (f2bf(s[7]) << 16);
      *(uint4*)(zb + ((size_t)nn << 6) + c8) = p;
    }
  }
  if (wv == 0) {
    float eln = sel[0][lane] + sel[1][lane] + sel[2][lane] + sel[3][lane];
    float ern = ser[0][lane] + ser[1][lane] + ser[2][lane] + ser[3][lane];
    if (n < N) {
      el[n] = eln;
      er[n] = ern;
    }
    float mx = (n < N) ? eln : -1e30f;
#pragma unroll
    for (int off = 32; off > 0; off >>= 1) mx = fmaxf(mx, __shfl_xor(mx, off));
    if (lane == 0) atomicMax(genc, enc_f32(mx));
  }
}

// == fused GAT aggregation, single pass (upper-bound max), bf16 z 16-lane/edge ==
__global__ __launch_bounds__(256) void gat_fused(
    const ushort* __restrict__ zb, const float* __restrict__ el,
    const float* __restrict__ er, const int* __restrict__ rowptr,
    const int* __restrict__ srcet, const unsigned* __restrict__ genc,
    float* __restrict__ hg, int N) {
  const int n = blockIdx.x * 4 + (threadIdx.x >> 6);
  const int lane = threadIdx.x & 63;
  const int g = lane >> 4;
  const int t = lane & 15;
  if (n >= N) return;
  const int beg = rowptr[n], end = rowptr[n + 1];
  const float ern = er[n];
  float mb = dec_f32(*genc) + ern;
  mb = (mb > 0.f) ? mb : 0.2f * mb;

  float4 num = make_float4(0.f, 0.f, 0.f, 0.f);
  float den = 0.f;
  for (int j = beg + g; j < end; j += 4) {
    const int se = srcet[j];
    const int s = se >> 2;
    float x = el[s] + ern;
    x = (x > 0.f) ? x : 0.2f * x;
    const float w = __expf(x - mb);
    den += w;
    const uint2 r = *(const uint2*)(zb + ((size_t)s << 6) + (t << 2));
    const float4 v = unpack4(r);
    num.x = fmaf(w, v.x, num.x);
    num.y = fmaf(w, v.y, num.y);
    num.z = fmaf(w, v.z, num.z);
    num.w = fmaf(w, v.w, num.w);
  }
#pragma unroll
  for (int off = 16; off <= 32; off <<= 1) {
    num.x += __shfl_xor(num.x, off);
    num.y += __shfl_xor(num.y, off);
    num.z += __shfl_xor(num.z, off);
    num.w += __shfl_xor(num.w, off);
    den += __shfl_xor(den, off);
  }
  if (g == 0) {
    const float inv = 1.f / fmaxf(den, 1e-9f);
    float4 o = make_float4(num.x * inv, num.y * inv, num.z * inv, num.w * inv);
    *(float4*)(hg + ((size_t)n << 6) + (t << 2)) = o;
  }
}

// ================= pooled head, two-level =================
__global__ __launch_bounds__(256) void pool_head2(
    const float* __restrict__ hg, const float* __restrict__ Wd,
    const int* __restrict__ gids, float* __restrict__ out, int N, int B) {
  __shared__ float acc[1024];
  for (int i = threadIdx.x; i < B; i += 256) acc[i] = 0.f;
  __syncthreads();

  const int wv = threadIdx.x >> 6;
  const int lane = threadIdx.x & 63;
  const int sub = lane & 3;
  const int idx = lane >> 2;

  const float4 w0 = *(const float4*)(Wd + (sub << 4) + 0);
  const float4 w1 = *(const float4*)(Wd + (sub << 4) + 4);
  const float4 w2 = *(const float4*)(Wd + (sub << 4) + 8);
  const float4 w3 = *(const float4*)(Wd + (sub << 4) + 12);

  const int base0 = blockIdx.x * POOL_NPB;
#pragma unroll 1
  for (int it = 0; it < POOL_NPB / 64; ++it) {
    const int n = base0 + it * 64 + wv * 16 + idx;
    if (n < N) {
      const float* p = hg + ((size_t)n << 6) + (sub << 4);
      const float4 v0 = *(const float4*)(p + 0);
      const float4 v1 = *(const float4*)(p + 4);
      const float4 v2 = *(const float4*)(p + 8);
      const float4 v3 = *(const float4*)(p + 12);
      float s = v0.x * w0.x + v0.y * w0.y + v0.z * w0.z + v0.w * w0.w;
      s = fmaf(v1.x, w1.x, s); s = fmaf(v1.y, w1.y, s);
      s = fmaf(v1.z, w1.z, s); s = fmaf(v1.w, w1.w, s);
      s = fmaf(v2.x, w2.x, s); s = fmaf(v2.y, w2.y, s);
      s = fmaf(v2.z, w2.z, s); s = fmaf(v2.w, w2.w, s);
      s = fmaf(v3.x, w3.x, s); s = fmaf(v3.y, w3.y, s);
      s = fmaf(v3.z, w3.z, s); s = fmaf(v3.w, w3.w, s);
      s += __shfl_xor(s, 1);
      s += __shfl_xor(s, 2);
      if (sub == 0) atomicAdd(&acc[gids[n]], s);
    }
  }
  __syncthreads();
  for (int i = threadIdx.x; i < B; i += 256) {
    const float v = acc[i];
    if (v != 0.f) unsafeAtomicAdd(out + i, v);
  }
}

__global__ void init_out_k(float* out, const float* bd, int n, unsigned* genc,
                           int* gcur, int CAP) {
  int i = blockIdx.x * blockDim.x + threadIdx.x;
  if (i < n) out[i] = bd[0];
  if (i < 256) gcur[i] = i * CAP;
  if (i == 0) *genc = enc_f32(-1e30f);
}

// ================= launch =================
extern "C" void kernel_launch(void* const* d_in, const int* in_sizes, int n_in,
                              void* d_out, int out_size, void* d_ws,
                              size_t ws_size, hipStream_t stream) {
  const float* h0 = (const float*)d_in[0];
  const float* Wrel = (const float*)d_in[1];
  const float* Wloop = (const float*)d_in[2];
  const float* brel = (const float*)d_in[3];
  const float* Wg = (const float*)d_in[4];
  const float* al = (const float*)d_in[5];
  const float* ar = (const float*)d_in[6];
  const float* Wd = (const float*)d_in[7];
  const float* bd = (const float*)d_in[8];
  const int* src = (const int*)d_in[9];
  const int* dst = (const int*)d_in[10];
  const int* et = (const int*)d_in[11];
  const int* gids = (const int*)d_in[12];

  const int N = in_sizes[0] / DD;
  const int E = in_sizes[9];
  const int L = in_sizes[2] / (DD * DD);
  float* out = (float*)d_out;
  const int CAP = (E / 256) * 2;  // fixed bucket capacity (2x mean)

  // ---- workspace layout ----
  char* wsb = (char*)d_ws;
  ushort* hbA = (ushort*)wsb;                    // N*64 bf16
  ushort* hbB = hbA + (size_t)N * DD;            // N*64 bf16
  ushort* aggr_bf = hbB + (size_t)N * DD;        // N*256 bf16 (25.6MB region)
  int* rowptr = (int*)(aggr_bf + (size_t)N * 256);  // N+1
  int* srcet = rowptr + N + 1;                   // E
  float* el = (float*)(srcet + E);               // N
  float* er = el + N;                            // N
  int* gcur = (int*)(er + N);                    // 256
  int* cbase = gcur + 256;                       // 256
  unsigned* genc = (unsigned*)(cbase + 256);     // 1
  unsigned* staging = (unsigned*)aggr_bf;        // 256*CAP uints (12.8MB)
  float* hg = (float*)aggr_bf;                   // f32 overlay after last dense

  dim3 b256(256);
  const int grid_dense = (N + 63) / 64;
  const int grid_n4 = (N + 3) / 4;
  const int nfb = (E + EPB - 1) / EPB;
  const int ncb = (N + 255) >> 8;

  hipLaunchKernelGGL(init_out_k, dim3((max(out_size, 256) + 255) / 256), b256,
                     0, stream, out, bd, out_size, genc, gcur, CAP);

  // ---- CSR build (fixed-capacity buckets, (dst,rel)-sorted output) ----
  hipLaunchKernelGGL(f2_coarse, dim3(nfb), b256, 0, stream, src, dst, et, gcur,
                     staging, E);
  hipLaunchKernelGGL(cscan2, dim3(1), b256, 0, stream, gcur, cbase, rowptr, N,
                     E, CAP);
  hipLaunchKernelGGL(f3_fine4, dim3(ncb * 4), b256, 0, stream, staging, gcur,
                     cbase, rowptr, srcet, N, CAP);

  // ---- h0 -> bf16 ----
  hipLaunchKernelGGL(conv_bf16, dim3((N * DD / 4 + 255) / 256), b256, 0, stream,
                     h0, hbA, N * DD / 4);

  // ---- RGCN layers (bf16 features, f32 accumulate; dense stores post-relu) ----
  ushort* cur = hbA;
  ushort* nxt = hbB;
  for (int l = 0; l < L; ++l) {
    hipLaunchKernelGGL(gather_rel, dim3(grid_n4), b256, 0, stream, cur, rowptr,
                       srcet, aggr_bf, N);
    hipLaunchKernelGGL(rgcn_dense_t, dim3(grid_dense), b256, 0, stream, aggr_bf,
                       cur, Wrel + (size_t)l * 4 * DD * DD,
                       Wloop + (size_t)l * DD * DD, brel + (size_t)l * DD, nxt,
                       N);
    ushort* tmp = cur; cur = nxt; nxt = tmp;
  }

  // ---- GAT ----
  ushort* zb = nxt;
  hipLaunchKernelGGL(gemm_gat_t, dim3(grid_dense), b256, 0, stream, cur, Wg, al,
                     ar, zb, el, er, genc, N);
  hipLaunchKernelGGL(gat_fused, dim3(grid_n4), b256, 0, stream, zb, el, er,
                     rowptr, srcet, genc, hg, N);

  const int grid_pool = (N + POOL_NPB - 1) / POOL_NPB;
  hipLaunchKernelGGL(pool_head2, dim3(grid_pool), b256, 0, stream, hg, Wd, gids,
                     out, N, out_size);
}